// Round 2
// baseline (2756.546 us; speedup 1.0000x reference)
//
#include <hip/hip_runtime.h>
#include <hip/hip_cooperative_groups.h>
#include <cmath>

namespace cg = cooperative_groups;

#define BB 16
#define NN 1024
#define MM 1024

// ---- persistent-kernel geometry ----
#define RPB  16            // rows per block (kr[16][4] = 64 VGPRs of K data)
#define NGRP (NN / RPB)    // 64 row-groups per batch
#define NBLK (BB * NGRP)   // 1024 blocks = 4 blocks/CU x 256 CUs, exactly co-resident

// ---- legacy (fallback) geometry ----
#define RPB8  8
#define NSLAB (NN / RPB8)  // 128 slabs per batch

static constexpr float INV_TAU = 20.0f;   // 1/0.05
static constexpr float LR   = 0.5f;
static constexpr float B1f  = 0.9f;
static constexpr float B2f  = 0.999f;
static constexpr float EPSA = 1e-8f;
// Clamp the exp ARGUMENT (survives -ffinite-math-only; result-clamp is folded
// away under fast-math).
static constexpr float EXP_CAP = 88.0f;

// d_ws layout (floats): u v mu vu mv vv, then part region.
// persistent path: part[BB][NGRP][MM] float2 = 8 MB
// legacy path:     part[BB][NSLAB][MM] float2 = 16 MB
#define OFF_U    0
#define OFF_V    16384
#define OFF_MU   32768
#define OFF_VU   49152
#define OFF_MV   65536
#define OFF_VV   81920
#define OFF_PART 98304

// ============================================================================
// Persistent cooperative kernel: K lives in VGPRs for all 10 iterations.
// Grid = 1024 blocks x 256 threads. Each block owns 16 rows of one batch;
// thread tid owns columns 4*tid..4*tid+3 (float4 lanes) => kr[16][4].
// Per iteration:
//   row pass : per-row max (wave butterfly + LDS cross-wave), exp-sum, Adam u
//   col pass : per-column (max,sum) partials over the 16 register rows
//   grid.sync
//   combine  : every block reduces 64 group-partials for 16 columns, Adam v
//   grid.sync
// Finalize: out = exp(kr + u + v) straight from registers.
// ============================================================================
__global__ __launch_bounds__(256, 4) void sinkhorn_persistent(
    const float* __restrict__ la, const float* __restrict__ log_a,
    const float* __restrict__ log_b, float* __restrict__ ws,
    float2* __restrict__ part, float* __restrict__ out)
{
    const int bid  = blockIdx.x;
    const int b    = bid >> 6;          // batch
    const int g    = bid & 63;          // row-group within batch
    const int row0 = g * RPB;
    const int tid  = threadIdx.x;
    const int wave = tid >> 6;
    const int lane = tid & 63;

    __shared__ float  redm[4 * RPB];    // [wave][row] partial max
    __shared__ float  reds[4 * RPB];    // [wave][row] partial sum
    __shared__ float  fin[RPB];         // final row max
    __shared__ float  su[RPB];          // fresh u for this block's rows
    __shared__ float2 red2[16][16];     // combine: [chunk][col16]

    // zero Adam state (u v mu vu mv vv = 98304 floats) before first sync
    if (bid < 384) ws[bid * 256 + tid] = 0.0f;

    // ---- load K slab into registers once, pre-scaled (the 11x re-read killer) ----
    const float* Kb = la + ((size_t)b * NN + row0) * MM + 4 * tid;
    float kr[RPB][4];
#pragma unroll
    for (int r = 0; r < RPB; ++r) {
        const float4 k4 = *(const float4*)(Kb + (size_t)r * MM);
        kr[r][0] = k4.x * INV_TAU; kr[r][1] = k4.y * INV_TAU;
        kr[r][2] = k4.z * INV_TAU; kr[r][3] = k4.w * INV_TAU;
    }

    cg::grid_group grid = cg::this_grid();
    grid.sync();   // state zeroed, K resident

    float pb1 = 1.0f, pb2 = 1.0f;
    for (int t = 1; t <= 10; ++t) {
        pb1 *= B1f; pb2 *= B2f;
        const float bc1 = 1.0f - pb1, bc2 = 1.0f - pb2;

        // ---- row pass: max ----
        const float4 v4 = *(const float4*)(ws + OFF_V + b * MM + 4 * tid);
        const float vj[4] = {v4.x, v4.y, v4.z, v4.w};
#pragma unroll
        for (int r = 0; r < RPB; ++r) {
            float m = fmaxf(fmaxf(kr[r][0] + vj[0], kr[r][1] + vj[1]),
                            fmaxf(kr[r][2] + vj[2], kr[r][3] + vj[3]));
#pragma unroll
            for (int off = 32; off; off >>= 1) m = fmaxf(m, __shfl_xor(m, off, 64));
            if (lane == 0) redm[wave * RPB + r] = m;
        }
        __syncthreads();
        if (tid < RPB)
            fin[tid] = fmaxf(fmaxf(redm[tid], redm[RPB + tid]),
                             fmaxf(redm[2 * RPB + tid], redm[3 * RPB + tid]));
        __syncthreads();

        // ---- row pass: exp-sum ----
#pragma unroll
        for (int r = 0; r < RPB; ++r) {
            const float Mr = fin[r];
            float s = __expf(kr[r][0] + vj[0] - Mr) + __expf(kr[r][1] + vj[1] - Mr)
                    + __expf(kr[r][2] + vj[2] - Mr) + __expf(kr[r][3] + vj[3] - Mr);
#pragma unroll
            for (int off = 32; off; off >>= 1) s += __shfl_xor(s, off, 64);
            if (lane == 0) reds[wave * RPB + r] = s;
        }
        __syncthreads();
        if (tid < RPB) {
            const int r  = tid;
            const int gi = b * NN + row0 + r;
            const float S   = reds[r] + reds[RPB + r] + reds[2 * RPB + r] + reds[3 * RPB + r];
            const float lse = fin[r] + __logf(S);
            const float uo  = ws[OFF_U + gi];
            const float gu  = (log_a[gi] - lse) - uo;
            const float m_  = B1f * ws[OFF_MU + gi] + (1.f - B1f) * gu;
            const float v_  = B2f * ws[OFF_VU + gi] + (1.f - B2f) * gu * gu;
            ws[OFF_MU + gi] = m_;
            ws[OFF_VU + gi] = v_;
            const float un  = uo + LR * (m_ / bc1) / (sqrtf(v_ / bc2) + EPSA);
            ws[OFF_U + gi]  = un;
            su[r] = un;
        }
        __syncthreads();

        // ---- col partials from the same registers (fresh u) ----
        {
            float2* p = part + ((size_t)b * NGRP + g) * MM + 4 * tid;
#pragma unroll
            for (int j = 0; j < 4; ++j) {
                float m = kr[0][j] + su[0];
#pragma unroll
                for (int r = 1; r < RPB; ++r) m = fmaxf(m, kr[r][j] + su[r]);
                float s = 0.f;
#pragma unroll
                for (int r = 0; r < RPB; ++r) s += __expf(kr[r][j] + su[r] - m);
                p[j] = make_float2(m, s);
            }
        }
        grid.sync();   // all partials visible

        // ---- combine + Adam v: every block handles 16 columns of its batch ----
        {
            const int cb  = bid >> 6;        // batch (== b)
            const int mg  = bid & 63;        // column group of 16
            const int c16 = tid & 15;
            const int q   = tid >> 4;        // chunk of 4 row-groups
            const float2* pp = part + ((size_t)cb * NGRP + q * 4) * MM + (mg * 16 + c16);
            float Mc = -3.0e38f, Sc = 0.f;
#pragma unroll
            for (int s = 0; s < 4; ++s) {
                const float2 pr = pp[(size_t)s * MM];
                const float mn = fmaxf(Mc, pr.x);
                Sc = Sc * __expf(Mc - mn) + pr.y * __expf(pr.x - mn);
                Mc = mn;
            }
            red2[q][c16] = make_float2(Mc, Sc);
            __syncthreads();
            if (tid < 16) {
                float M = -3.0e38f, S = 0.f;
#pragma unroll
                for (int q2 = 0; q2 < 16; ++q2) {
                    const float2 pr = red2[q2][tid];
                    const float mn = fmaxf(M, pr.x);
                    S = S * __expf(M - mn) + pr.y * __expf(pr.x - mn);
                    M = mn;
                }
                const int i     = cb * MM + mg * 16 + tid;
                const float lse = M + __logf(S);
                const float vo  = ws[OFF_V + i];
                const float gv  = (log_b[i] - lse) - vo;
                const float m_  = B1f * ws[OFF_MV + i] + (1.f - B1f) * gv;
                const float v_  = B2f * ws[OFF_VV + i] + (1.f - B2f) * gv * gv;
                ws[OFF_MV + i] = m_;
                ws[OFF_VV + i] = v_;
                ws[OFF_V + i]  = vo + LR * (m_ / bc1) / (sqrtf(v_ / bc2) + EPSA);
            }
        }
        grid.sync();   // fresh v visible for next row pass
    }

    // ---- finalize from registers: out = exp(K/tau + u + v), arg-clamped ----
    const float4 vf = *(const float4*)(ws + OFF_V + b * MM + 4 * tid);
    float* ob = out + ((size_t)b * NN + row0) * MM + 4 * tid;
#pragma unroll
    for (int r = 0; r < RPB; ++r) {
        const float uu = su[r];
        float4 o;
        o.x = __expf(fminf(kr[r][0] + uu + vf.x, EXP_CAP));
        o.y = __expf(fminf(kr[r][1] + uu + vf.y, EXP_CAP));
        o.z = __expf(fminf(kr[r][2] + uu + vf.z, EXP_CAP));
        o.w = __expf(fminf(kr[r][3] + uu + vf.w, EXP_CAP));
        *(float4*)(ob + (size_t)r * MM) = o;
    }
}

// ============================================================================
// Legacy fallback path (the verified 339 us kernel) — used only if the
// cooperative launch is rejected (occupancy or capture limitation).
// ============================================================================
__global__ void init_state(float* __restrict__ ws) {
    int i = blockIdx.x * 256 + threadIdx.x;   // 384 blocks
    ws[i] = 0.0f;
}

__global__ __launch_bounds__(256, 4) void iter_fused(
    const float* __restrict__ la, const float* __restrict__ log_a,
    float* __restrict__ ws, float2* __restrict__ part,
    float bc1, float bc2)
{
    const int slab = blockIdx.x;
    const int b    = blockIdx.y;
    const int row0 = slab * RPB8;
    const int tid  = threadIdx.x;
    const int wave = tid >> 6;
    const int lane = tid & 63;
    __shared__ float redm[4 * RPB8];
    __shared__ float reds[4 * RPB8];
    __shared__ float fin[RPB8];
    __shared__ float su[RPB8];

    const float* Kb = la + ((size_t)b * NN + row0) * MM + 4 * tid;
    float kr[RPB8][4];
#pragma unroll
    for (int r = 0; r < RPB8; ++r) {
        const float4 k4 = *(const float4*)(Kb + (size_t)r * MM);
        kr[r][0] = k4.x * INV_TAU; kr[r][1] = k4.y * INV_TAU;
        kr[r][2] = k4.z * INV_TAU; kr[r][3] = k4.w * INV_TAU;
    }
    const float4 v4 = *(const float4*)(ws + OFF_V + b * MM + 4 * tid);
    const float vj[4] = {v4.x, v4.y, v4.z, v4.w};

    float pm[RPB8];
#pragma unroll
    for (int r = 0; r < RPB8; ++r)
        pm[r] = fmaxf(fmaxf(kr[r][0] + vj[0], kr[r][1] + vj[1]),
                      fmaxf(kr[r][2] + vj[2], kr[r][3] + vj[3]));
#pragma unroll
    for (int off = 32; off; off >>= 1)
#pragma unroll
        for (int r = 0; r < RPB8; ++r)
            pm[r] = fmaxf(pm[r], __shfl_xor(pm[r], off, 64));
    if (lane == 0)
#pragma unroll
        for (int r = 0; r < RPB8; ++r) redm[wave * RPB8 + r] = pm[r];
    __syncthreads();
    if (tid < RPB8)
        fin[tid] = fmaxf(fmaxf(redm[tid], redm[RPB8 + tid]),
                         fmaxf(redm[2 * RPB8 + tid], redm[3 * RPB8 + tid]));
    __syncthreads();
    float Mr[RPB8];
#pragma unroll
    for (int r = 0; r < RPB8; ++r) Mr[r] = fin[r];

    float ps[RPB8];
#pragma unroll
    for (int r = 0; r < RPB8; ++r)
        ps[r] = __expf(kr[r][0] + vj[0] - Mr[r]) + __expf(kr[r][1] + vj[1] - Mr[r])
              + __expf(kr[r][2] + vj[2] - Mr[r]) + __expf(kr[r][3] + vj[3] - Mr[r]);
#pragma unroll
    for (int off = 32; off; off >>= 1)
#pragma unroll
        for (int r = 0; r < RPB8; ++r)
            ps[r] += __shfl_xor(ps[r], off, 64);
    if (lane == 0)
#pragma unroll
        for (int r = 0; r < RPB8; ++r) reds[wave * RPB8 + r] = ps[r];
    __syncthreads();
    if (tid < RPB8) {
        const int r  = tid;
        const int gi = b * NN + row0 + r;
        const float S   = reds[r] + reds[RPB8 + r] + reds[2 * RPB8 + r] + reds[3 * RPB8 + r];
        const float lse = Mr[r] + __logf(S);
        const float uo  = ws[OFF_U + gi];
        const float gu  = (log_a[gi] - lse) - uo;
        const float m_  = B1f * ws[OFF_MU + gi] + (1.f - B1f) * gu;
        const float v_  = B2f * ws[OFF_VU + gi] + (1.f - B2f) * gu * gu;
        ws[OFF_MU + gi] = m_;
        ws[OFF_VU + gi] = v_;
        const float un  = uo + LR * (m_ / bc1) / (sqrtf(v_ / bc2) + EPSA);
        ws[OFF_U + gi]  = un;
        su[r] = un;
    }
    __syncthreads();
    float uu[RPB8];
#pragma unroll
    for (int r = 0; r < RPB8; ++r) uu[r] = su[r];

    float2 out4[4];
#pragma unroll
    for (int j = 0; j < 4; ++j) {
        float m = kr[0][j] + uu[0];
#pragma unroll
        for (int r = 1; r < RPB8; ++r) m = fmaxf(m, kr[r][j] + uu[r]);
        float s = 0.f;
#pragma unroll
        for (int r = 0; r < RPB8; ++r) s += __expf(kr[r][j] + uu[r] - m);
        out4[j] = make_float2(m, s);
    }
    float2* p = part + ((size_t)b * NSLAB + slab) * MM + 4 * tid;
    p[0] = out4[0]; p[1] = out4[1]; p[2] = out4[2]; p[3] = out4[3];
}

__global__ __launch_bounds__(256, 8) void combine_legacy(
    const float* __restrict__ log_b, float* __restrict__ ws,
    const float2* __restrict__ part, float bc1, float bc2)
{
    const int b   = blockIdx.x >> 4;
    const int mg  = blockIdx.x & 15;
    const int tid = threadIdx.x;
    const int c   = tid & 63;
    const int q   = tid >> 6;
    const int m   = mg * 64 + c;
    __shared__ float2 red[4][64];

    const float2* p = part + ((size_t)b * NSLAB + q * 32) * MM + m;
    float M = -3.0e38f, S = 0.f;
#pragma unroll 8
    for (int s = 0; s < 32; ++s) {
        const float2 pr = p[(size_t)s * MM];
        const float mn = fmaxf(M, pr.x);
        S = S * __expf(M - mn) + pr.y * __expf(pr.x - mn);
        M = mn;
    }
    red[q][c] = make_float2(M, S);
    __syncthreads();
    if (q == 0) {
        const float2 a = red[0][c], bb = red[1][c], cc = red[2][c], d = red[3][c];
        const float Mt = fmaxf(fmaxf(a.x, bb.x), fmaxf(cc.x, d.x));
        const float St = a.y * __expf(a.x - Mt) + bb.y * __expf(bb.x - Mt)
                       + cc.y * __expf(cc.x - Mt) + d.y * __expf(d.x - Mt);
        const int i = b * MM + m;
        const float lse = Mt + __logf(St);
        const float vo  = ws[OFF_V + i];
        const float gv  = (log_b[i] - lse) - vo;
        const float m_  = B1f * ws[OFF_MV + i] + (1.f - B1f) * gv;
        const float v_  = B2f * ws[OFF_VV + i] + (1.f - B2f) * gv * gv;
        ws[OFF_MV + i] = m_;
        ws[OFF_VV + i] = v_;
        ws[OFF_V + i]  = vo + LR * (m_ / bc1) / (sqrtf(v_ / bc2) + EPSA);
    }
}

__global__ void finalize_legacy(const float* __restrict__ la, const float* __restrict__ ws,
                                float* __restrict__ out)
{
    const size_t i4 = (size_t)blockIdx.x * 256 + threadIdx.x;
    const size_t e  = i4 * 4;
    const int row = (int)(e >> 10);
    const int b   = row >> 10;
    const int m   = (int)(e & 1023);
    const float uu = ws[OFF_U + row];
    const float4 k4 = ((const float4*)la)[i4];
    const float4 v4 = *(const float4*)(ws + OFF_V + b * MM + m);
    float4 o;
    o.x = __expf(fminf(k4.x * INV_TAU + uu + v4.x, EXP_CAP));
    o.y = __expf(fminf(k4.y * INV_TAU + uu + v4.y, EXP_CAP));
    o.z = __expf(fminf(k4.z * INV_TAU + uu + v4.z, EXP_CAP));
    o.w = __expf(fminf(k4.w * INV_TAU + uu + v4.w, EXP_CAP));
    ((float4*)out)[i4] = o;
}

extern "C" void kernel_launch(void* const* d_in, const int* in_sizes, int n_in,
                              void* d_out, int out_size, void* d_ws, size_t ws_size,
                              hipStream_t stream) {
    const float* la    = (const float*)d_in[0];
    const float* log_a = (const float*)d_in[1];
    const float* log_b = (const float*)d_in[2];
    float*  out  = (float*)d_out;
    float*  ws   = (float*)d_ws;
    float2* part = (float2*)(ws + OFF_PART);

    void* args[] = {(void*)&la, (void*)&log_a, (void*)&log_b,
                    (void*)&ws, (void*)&part, (void*)&out};
    hipError_t err = hipLaunchCooperativeKernel(
        (const void*)sinkhorn_persistent, dim3(NBLK), dim3(256), args, 0, stream);

    if (err != hipSuccess) {
        // Fallback: previous verified multi-kernel path (339 us).
        init_state<<<384, 256, 0, stream>>>(ws);
        for (int t = 1; t <= 10; ++t) {
            const float bc1 = 1.0f - powf(B1f, (float)t);
            const float bc2 = 1.0f - powf(B2f, (float)t);
            iter_fused<<<dim3(NSLAB, BB), 256, 0, stream>>>(la, log_a, ws, part, bc1, bc2);
            combine_legacy<<<BB * MM / 256, 256, 0, stream>>>(log_b, ws, part, bc1, bc2);
        }
        finalize_legacy<<<16384, 256, 0, stream>>>(la, ws, out);
    }
}

// Round 3
// 1413.661 us; speedup vs baseline: 1.9499x; 1.9499x over previous
//
#include <hip/hip_runtime.h>
#include <cmath>

#define BB 16
#define NN 1024
#define MM 1024

// ---- persistent-kernel geometry ----
// 512 blocks x 256 threads, 2 blocks/CU co-resident (launch_bounds(256,2) ->
// 256-VGPR cap => kr[32][4]=128 VGPRs + ~50 working fits with big headroom;
// the R2 failure was kr spilling to scratch at the 128-VGPR cap + cg::sync).
#define RPB  32            // rows per block
#define NGRP (NN / RPB)    // 32 row-groups per batch
#define NBLK (BB * NGRP)   // 512 blocks

// ---- legacy (fallback) geometry ----
#define RPB8  8
#define NSLAB (NN / RPB8)  // 128 slabs per batch

static constexpr float INV_TAU = 20.0f;   // 1/0.05
static constexpr float LR   = 0.5f;
static constexpr float B1f  = 0.9f;
static constexpr float B2f  = 0.999f;
static constexpr float EPSA = 1e-8f;
// Clamp the exp ARGUMENT (survives -ffinite-math-only; result-clamp is folded
// away under fast-math).
static constexpr float EXP_CAP = 88.0f;

// d_ws layout (floats): u v mu vu mv vv, then barrier counter, then part region.
#define OFF_U    0
#define OFF_V    16384
#define OFF_MU   32768
#define OFF_VU   49152
#define OFF_MV   65536
#define OFF_VV   81920
#define OFF_CNT  98304     // int barrier counter (16 slots reserved)
#define OFF_PART 98320     // float2 region

// ---- hand-rolled grid barrier: no cg, fully inline, monotonic counter ----
// Writer side: full agent fence (L2 writeback) then relaxed atomic inc.
// Reader side: relaxed spin until count reaches epoch*NBLK, then full agent
// fence (L2/L1 invalidate) so subsequent normal loads see remote stores.
__device__ __forceinline__ void gbar(int* cnt, int& ep) {
    __syncthreads();
    ++ep;
    if (threadIdx.x == 0) {
        __threadfence();   // release: wb+inv L2 so this block's stores are visible
        __hip_atomic_fetch_add(cnt, 1, __ATOMIC_RELAXED, __HIP_MEMORY_SCOPE_AGENT);
        const int tgt = ep * NBLK;
        while (__hip_atomic_load(cnt, __ATOMIC_RELAXED, __HIP_MEMORY_SCOPE_AGENT) < tgt)
            __builtin_amdgcn_s_sleep(2);
        __threadfence();   // acquire: invalidate L1/L2 before reading remote data
    }
    __syncthreads();
}

// ============================================================================
// Persistent kernel: K lives in VGPRs (kr[32][4]) for all 10 iterations.
// Block (b,g) owns rows g*32..g*32+31 of batch b; thread tid owns columns
// 4*tid..4*tid+3. Per iteration: row lse + Adam u; col partials from the same
// registers; grid barrier; combine (block (b,g) reduces 32 group-partials for
// columns g*32..g*32+31) + Adam v; grid barrier. Finalize from registers.
// ============================================================================
__global__ __launch_bounds__(256, 2) void sinkhorn_persistent(
    const float* __restrict__ la, const float* __restrict__ log_a,
    const float* __restrict__ log_b, float* __restrict__ ws,
    float2* __restrict__ part, float* __restrict__ out)
{
    const int bid  = blockIdx.x;
    const int b    = bid >> 5;          // batch
    const int g    = bid & 31;          // row-group AND column-group
    const int row0 = g * RPB;
    const int tid  = threadIdx.x;
    const int wave = tid >> 6;
    const int lane = tid & 63;

    __shared__ float  redm[4 * RPB];    // [wave][row] partial max
    __shared__ float  reds[4 * RPB];    // [wave][row] partial sum
    __shared__ float  fin[RPB];         // final row max
    __shared__ float  su[RPB];          // fresh u for this block's rows
    __shared__ float2 red2[8][32];      // combine: [chunk][col32]

    int* cnt = (int*)(ws + OFF_CNT);
    int ep = 0;

    // ---- load K slab into registers once, pre-scaled ----
    const float* Kb = la + ((size_t)b * NN + row0) * MM + 4 * tid;
    float kr[RPB][4];
#pragma unroll
    for (int r = 0; r < RPB; ++r) {
        const float4 k4 = *(const float4*)(Kb + (size_t)r * MM);
        kr[r][0] = k4.x * INV_TAU; kr[r][1] = k4.y * INV_TAU;
        kr[r][2] = k4.z * INV_TAU; kr[r][3] = k4.w * INV_TAU;
    }

    float pb1 = 1.0f, pb2 = 1.0f;
    for (int t = 0; t < 10; ++t) {
        pb1 *= B1f; pb2 *= B2f;
        const float bc1 = 1.0f - pb1, bc2 = 1.0f - pb2;

        // ---- row pass: max ----
        const float4 v4 = *(const float4*)(ws + OFF_V + b * MM + 4 * tid);
#pragma unroll
        for (int r = 0; r < RPB; ++r) {
            float m = fmaxf(fmaxf(kr[r][0] + v4.x, kr[r][1] + v4.y),
                            fmaxf(kr[r][2] + v4.z, kr[r][3] + v4.w));
#pragma unroll
            for (int off = 32; off; off >>= 1) m = fmaxf(m, __shfl_xor(m, off, 64));
            if (lane == 0) redm[wave * RPB + r] = m;
        }
        __syncthreads();
        if (tid < RPB)
            fin[tid] = fmaxf(fmaxf(redm[tid], redm[RPB + tid]),
                             fmaxf(redm[2 * RPB + tid], redm[3 * RPB + tid]));
        __syncthreads();

        // ---- row pass: exp-sum ----
#pragma unroll
        for (int r = 0; r < RPB; ++r) {
            const float Mr = fin[r];
            float s = __expf(kr[r][0] + v4.x - Mr) + __expf(kr[r][1] + v4.y - Mr)
                    + __expf(kr[r][2] + v4.z - Mr) + __expf(kr[r][3] + v4.w - Mr);
#pragma unroll
            for (int off = 32; off; off >>= 1) s += __shfl_xor(s, off, 64);
            if (lane == 0) reds[wave * RPB + r] = s;
        }
        __syncthreads();
        if (tid < RPB) {
            const int r  = tid;
            const int gi = b * NN + row0 + r;
            const float S   = reds[r] + reds[RPB + r] + reds[2 * RPB + r] + reds[3 * RPB + r];
            const float lse = fin[r] + __logf(S);
            const float uo  = ws[OFF_U + gi];
            const float gu  = (log_a[gi] - lse) - uo;
            const float m_  = B1f * ws[OFF_MU + gi] + (1.f - B1f) * gu;
            const float v_  = B2f * ws[OFF_VU + gi] + (1.f - B2f) * gu * gu;
            ws[OFF_MU + gi] = m_;
            ws[OFF_VU + gi] = v_;
            const float un  = uo + LR * (m_ / bc1) / (sqrtf(v_ / bc2) + EPSA);
            ws[OFF_U + gi]  = un;
            su[r] = un;
        }
        __syncthreads();

        // ---- col partials: exact two-pass over registers (fresh u) ----
        {
            float2* p = part + ((size_t)b * NGRP + g) * MM + 4 * tid;
#pragma unroll
            for (int j = 0; j < 4; ++j) {
                float m = kr[0][j] + su[0];
#pragma unroll
                for (int r = 1; r < RPB; ++r) m = fmaxf(m, kr[r][j] + su[r]);
                float s = 0.f;
#pragma unroll
                for (int r = 0; r < RPB; ++r) s += __expf(kr[r][j] + su[r] - m);
                p[j] = make_float2(m, s);
            }
        }
        gbar(cnt, ep);   // all partials visible device-wide

        // ---- combine + Adam v: block (b,g) handles columns g*32..g*32+31 ----
        {
            const int c32 = tid & 31;
            const int q   = tid >> 5;        // 8 chunks of 4 row-groups
            const float2* pp = part + ((size_t)b * NGRP + q * 4) * MM + (g * 32 + c32);
            float Mc = -3.0e38f, Sc = 0.f;
#pragma unroll
            for (int s5 = 0; s5 < 4; ++s5) {
                const float2 pr = pp[(size_t)s5 * MM];
                const float mn = fmaxf(Mc, pr.x);
                Sc = Sc * __expf(Mc - mn) + pr.y * __expf(pr.x - mn);
                Mc = mn;
            }
            red2[q][c32] = make_float2(Mc, Sc);
            __syncthreads();
            if (tid < 32) {
                float M = -3.0e38f, S = 0.f;
#pragma unroll
                for (int q2 = 0; q2 < 8; ++q2) {
                    const float2 pr = red2[q2][tid];
                    const float mn = fmaxf(M, pr.x);
                    S = S * __expf(M - mn) + pr.y * __expf(pr.x - mn);
                    M = mn;
                }
                const int i     = b * MM + g * 32 + tid;
                const float lse = M + __logf(S);
                const float vo  = ws[OFF_V + i];
                const float gv  = (log_b[i] - lse) - vo;
                const float m_  = B1f * ws[OFF_MV + i] + (1.f - B1f) * gv;
                const float v_  = B2f * ws[OFF_VV + i] + (1.f - B2f) * gv * gv;
                ws[OFF_MV + i] = m_;
                ws[OFF_VV + i] = v_;
                ws[OFF_V + i]  = vo + LR * (m_ / bc1) / (sqrtf(v_ / bc2) + EPSA);
            }
        }
        gbar(cnt, ep);   // fresh v visible for next row pass
    }

    // ---- finalize from registers: out = exp(K/tau + u + v), arg-clamped ----
    const float4 vf = *(const float4*)(ws + OFF_V + b * MM + 4 * tid);
    float* ob = out + ((size_t)b * NN + row0) * MM + 4 * tid;
#pragma unroll
    for (int r = 0; r < RPB; ++r) {
        const float uu = su[r];
        float4 o;
        o.x = __expf(fminf(kr[r][0] + uu + vf.x, EXP_CAP));
        o.y = __expf(fminf(kr[r][1] + uu + vf.y, EXP_CAP));
        o.z = __expf(fminf(kr[r][2] + uu + vf.z, EXP_CAP));
        o.w = __expf(fminf(kr[r][3] + uu + vf.w, EXP_CAP));
        *(float4*)(ob + (size_t)r * MM) = o;
    }
}

// ============================================================================
// Legacy fallback path (the verified 339 us kernel) — used only if the
// cooperative launch is rejected.
// ============================================================================
__global__ __launch_bounds__(256, 4) void iter_fused(
    const float* __restrict__ la, const float* __restrict__ log_a,
    float* __restrict__ ws, float2* __restrict__ part,
    float bc1, float bc2)
{
    const int slab = blockIdx.x;
    const int b    = blockIdx.y;
    const int row0 = slab * RPB8;
    const int tid  = threadIdx.x;
    const int wave = tid >> 6;
    const int lane = tid & 63;
    __shared__ float redm[4 * RPB8];
    __shared__ float reds[4 * RPB8];
    __shared__ float fin[RPB8];
    __shared__ float su[RPB8];

    const float* Kb = la + ((size_t)b * NN + row0) * MM + 4 * tid;
    float kr[RPB8][4];
#pragma unroll
    for (int r = 0; r < RPB8; ++r) {
        const float4 k4 = *(const float4*)(Kb + (size_t)r * MM);
        kr[r][0] = k4.x * INV_TAU; kr[r][1] = k4.y * INV_TAU;
        kr[r][2] = k4.z * INV_TAU; kr[r][3] = k4.w * INV_TAU;
    }
    const float4 v4 = *(const float4*)(ws + OFF_V + b * MM + 4 * tid);
    const float vj[4] = {v4.x, v4.y, v4.z, v4.w};

    float pm[RPB8];
#pragma unroll
    for (int r = 0; r < RPB8; ++r)
        pm[r] = fmaxf(fmaxf(kr[r][0] + vj[0], kr[r][1] + vj[1]),
                      fmaxf(kr[r][2] + vj[2], kr[r][3] + vj[3]));
#pragma unroll
    for (int off = 32; off; off >>= 1)
#pragma unroll
        for (int r = 0; r < RPB8; ++r)
            pm[r] = fmaxf(pm[r], __shfl_xor(pm[r], off, 64));
    if (lane == 0)
#pragma unroll
        for (int r = 0; r < RPB8; ++r) redm[wave * RPB8 + r] = pm[r];
    __syncthreads();
    if (tid < RPB8)
        fin[tid] = fmaxf(fmaxf(redm[tid], redm[RPB8 + tid]),
                         fmaxf(redm[2 * RPB8 + tid], redm[3 * RPB8 + tid]));
    __syncthreads();
    float Mr[RPB8];
#pragma unroll
    for (int r = 0; r < RPB8; ++r) Mr[r] = fin[r];

    float ps[RPB8];
#pragma unroll
    for (int r = 0; r < RPB8; ++r)
        ps[r] = __expf(kr[r][0] + vj[0] - Mr[r]) + __expf(kr[r][1] + vj[1] - Mr[r])
              + __expf(kr[r][2] + vj[2] - Mr[r]) + __expf(kr[r][3] + vj[3] - Mr[r]);
#pragma unroll
    for (int off = 32; off; off >>= 1)
#pragma unroll
        for (int r = 0; r < RPB8; ++r)
            ps[r] += __shfl_xor(ps[r], off, 64);
    if (lane == 0)
#pragma unroll
        for (int r = 0; r < RPB8; ++r) reds[wave * RPB8 + r] = ps[r];
    __syncthreads();
    if (tid < RPB8) {
        const int r  = tid;
        const int gi = b * NN + row0 + r;
        const float S   = reds[r] + reds[RPB8 + r] + reds[2 * RPB8 + r] + reds[3 * RPB8 + r];
        const float lse = Mr[r] + __logf(S);
        const float uo  = ws[OFF_U + gi];
        const float gu  = (log_a[gi] - lse) - uo;
        const float m_  = B1f * ws[OFF_MU + gi] + (1.f - B1f) * gu;
        const float v_  = B2f * ws[OFF_VU + gi] + (1.f - B2f) * gu * gu;
        ws[OFF_MU + gi] = m_;
        ws[OFF_VU + gi] = v_;
        const float un  = uo + LR * (m_ / bc1) / (sqrtf(v_ / bc2) + EPSA);
        ws[OFF_U + gi]  = un;
        su[r] = un;
    }
    __syncthreads();
    float uu[RPB8];
#pragma unroll
    for (int r = 0; r < RPB8; ++r) uu[r] = su[r];

    float2 out4[4];
#pragma unroll
    for (int j = 0; j < 4; ++j) {
        float m = kr[0][j] + uu[0];
#pragma unroll
        for (int r = 1; r < RPB8; ++r) m = fmaxf(m, kr[r][j] + uu[r]);
        float s = 0.f;
#pragma unroll
        for (int r = 0; r < RPB8; ++r) s += __expf(kr[r][j] + uu[r] - m);
        out4[j] = make_float2(m, s);
    }
    float2* p = part + ((size_t)b * NSLAB + slab) * MM + 4 * tid;
    p[0] = out4[0]; p[1] = out4[1]; p[2] = out4[2]; p[3] = out4[3];
}

__global__ __launch_bounds__(256, 8) void combine_legacy(
    const float* __restrict__ log_b, float* __restrict__ ws,
    const float2* __restrict__ part, float bc1, float bc2)
{
    const int b   = blockIdx.x >> 4;
    const int mg  = blockIdx.x & 15;
    const int tid = threadIdx.x;
    const int c   = tid & 63;
    const int q   = tid >> 6;
    const int m   = mg * 64 + c;
    __shared__ float2 red[4][64];

    const float2* p = part + ((size_t)b * NSLAB + q * 32) * MM + m;
    float M = -3.0e38f, S = 0.f;
#pragma unroll 8
    for (int s = 0; s < 32; ++s) {
        const float2 pr = p[(size_t)s * MM];
        const float mn = fmaxf(M, pr.x);
        S = S * __expf(M - mn) + pr.y * __expf(pr.x - mn);
        M = mn;
    }
    red[q][c] = make_float2(M, S);
    __syncthreads();
    if (q == 0) {
        const float2 a = red[0][c], bb = red[1][c], cc = red[2][c], d = red[3][c];
        const float Mt = fmaxf(fmaxf(a.x, bb.x), fmaxf(cc.x, d.x));
        const float St = a.y * __expf(a.x - Mt) + bb.y * __expf(bb.x - Mt)
                       + cc.y * __expf(cc.x - Mt) + d.y * __expf(d.x - Mt);
        const int i = b * MM + m;
        const float lse = Mt + __logf(St);
        const float vo  = ws[OFF_V + i];
        const float gv  = (log_b[i] - lse) - vo;
        const float m_  = B1f * ws[OFF_MV + i] + (1.f - B1f) * gv;
        const float v_  = B2f * ws[OFF_VV + i] + (1.f - B2f) * gv * gv;
        ws[OFF_MV + i] = m_;
        ws[OFF_VV + i] = v_;
        ws[OFF_V + i]  = vo + LR * (m_ / bc1) / (sqrtf(v_ / bc2) + EPSA);
    }
}

__global__ void finalize_legacy(const float* __restrict__ la, const float* __restrict__ ws,
                                float* __restrict__ out)
{
    const size_t i4 = (size_t)blockIdx.x * 256 + threadIdx.x;
    const size_t e  = i4 * 4;
    const int row = (int)(e >> 10);
    const int b   = row >> 10;
    const int m   = (int)(e & 1023);
    const float uu = ws[OFF_U + row];
    const float4 k4 = ((const float4*)la)[i4];
    const float4 v4 = *(const float4*)(ws + OFF_V + b * MM + m);
    float4 o;
    o.x = __expf(fminf(k4.x * INV_TAU + uu + v4.x, EXP_CAP));
    o.y = __expf(fminf(k4.y * INV_TAU + uu + v4.y, EXP_CAP));
    o.z = __expf(fminf(k4.z * INV_TAU + uu + v4.z, EXP_CAP));
    o.w = __expf(fminf(k4.w * INV_TAU + uu + v4.w, EXP_CAP));
    ((float4*)out)[i4] = o;
}

extern "C" void kernel_launch(void* const* d_in, const int* in_sizes, int n_in,
                              void* d_out, int out_size, void* d_ws, size_t ws_size,
                              hipStream_t stream) {
    const float* la    = (const float*)d_in[0];
    const float* log_a = (const float*)d_in[1];
    const float* log_b = (const float*)d_in[2];
    float*  out  = (float*)d_out;
    float*  ws   = (float*)d_ws;
    float2* part = (float2*)(ws + OFF_PART);

    // Zero Adam state + barrier counter (graph-safe, replay-safe).
    hipMemsetAsync(d_ws, 0, (OFF_CNT + 16) * sizeof(float), stream);

    void* args[] = {(void*)&la, (void*)&log_a, (void*)&log_b,
                    (void*)&ws, (void*)&part, (void*)&out};
    hipError_t err = hipLaunchCooperativeKernel(
        (const void*)sinkhorn_persistent, dim3(NBLK), dim3(256), args, 0, stream);

    if (err != hipSuccess) {
        // Fallback: previous verified multi-kernel path (339 us).
        for (int t = 1; t <= 10; ++t) {
            const float bc1 = 1.0f - powf(B1f, (float)t);
            const float bc2 = 1.0f - powf(B2f, (float)t);
            iter_fused<<<dim3(NSLAB, BB), 256, 0, stream>>>(la, log_a, ws, part, bc1, bc2);
            combine_legacy<<<BB * MM / 256, 256, 0, stream>>>(log_b, ws, part, bc1, bc2);
        }
        finalize_legacy<<<16384, 256, 0, stream>>>(la, ws, out);
    }
}

// Round 5
// 1391.319 us; speedup vs baseline: 1.9812x; 1.0161x over previous
//
#include <hip/hip_runtime.h>
#include <cmath>

#define BB 16
#define NN 1024
#define MM 1024

// ---- persistent-kernel geometry ----
// 512 blocks x 256 threads, 2 blocks/CU co-resident.
// K residency is HYBRID: rows 0-15 in VGPRs (kr[16][4] = 64 regs), rows 16-31
// in LDS (64 KB). Peak live set ~115 VGPR -> no spill even if the allocator
// targets 4 waves/EU (the R2/R3 failure: allocator picked cap/2 and spilled
// the 128-reg kr array). amdgpu_waves_per_eu(2,2) additionally pins the
// occupancy target so the scheduler can't chase a higher notch.
#define RPB   32           // rows per block
#define RREG  16           // rows kept in registers
#define NGRP  (NN / RPB)   // 32 row-groups per batch
#define NBLK  (BB * NGRP)  // 512 blocks

// ---- legacy (fallback) geometry ----
#define RPB8  8
#define NSLAB (NN / RPB8)  // 128 slabs per batch

static constexpr float INV_TAU = 20.0f;   // 1/0.05
static constexpr float LR   = 0.5f;
static constexpr float B1f  = 0.9f;
static constexpr float B2f  = 0.999f;
static constexpr float EPSA = 1e-8f;
// Clamp the exp ARGUMENT (survives -ffinite-math-only; result-clamp is folded
// away under fast-math).
static constexpr float EXP_CAP = 88.0f;

// d_ws layout (floats): u v mu vu mv vv, then barrier counter, then part region.
#define OFF_U    0
#define OFF_V    16384
#define OFF_MU   32768
#define OFF_VU   49152
#define OFF_MV   65536
#define OFF_VV   81920
#define OFF_CNT  98304     // int barrier counter (16 slots reserved)
#define OFF_PART 98320     // float2 region

// ---- hand-rolled grid barrier (verified passing in R3): monotonic counter,
// agent-scope release/acquire fences in the leader thread. ----
__device__ __forceinline__ void gbar(int* cnt, int& ep) {
    __syncthreads();
    ++ep;
    if (threadIdx.x == 0) {
        __threadfence();   // release: wb L2 so this block's stores are visible
        __hip_atomic_fetch_add(cnt, 1, __ATOMIC_RELAXED, __HIP_MEMORY_SCOPE_AGENT);
        const int tgt = ep * NBLK;
        while (__hip_atomic_load(cnt, __ATOMIC_RELAXED, __HIP_MEMORY_SCOPE_AGENT) < tgt)
            __builtin_amdgcn_s_sleep(2);
        __threadfence();   // acquire: inv L1/L2 before reading remote data
    }
    __syncthreads();
}

// ============================================================================
// Persistent kernel. Block (b,g) owns rows g*32..g*32+31 of batch b; thread
// tid owns columns 4*tid..4*tid+3. Rows 0-15 in VGPRs, rows 16-31 in LDS.
// Per iteration: row lse + Adam u; col partials; grid barrier; combine +
// Adam v; grid barrier. Finalize from registers/LDS.
// ============================================================================
__global__ __launch_bounds__(256)
__attribute__((amdgpu_waves_per_eu(2, 2)))
void sinkhorn_persistent(
    const float* __restrict__ la, const float* __restrict__ log_a,
    const float* __restrict__ log_b, float* __restrict__ ws,
    float2* __restrict__ part, float* __restrict__ out)
{
    const int bid  = blockIdx.x;
    const int b    = bid >> 5;          // batch
    const int g    = bid & 31;          // row-group AND column-group
    const int row0 = g * RPB;
    const int tid  = threadIdx.x;
    const int wave = tid >> 6;
    const int lane = tid & 63;

    __shared__ float  klds[RPB - RREG][MM];   // rows 16-31, pre-scaled (64 KB)
    __shared__ float  redm[4 * RPB];    // [wave][row] partial max
    __shared__ float  reds[4 * RPB];    // [wave][row] partial sum
    __shared__ float  fin[RPB];         // final row max
    __shared__ float  su[RPB];          // fresh u for this block's rows
    __shared__ float2 red2[8][32];      // combine: [chunk][col32]

    int* cnt = (int*)(ws + OFF_CNT);
    int ep = 0;

    // ---- load K slab: rows 0-15 -> registers, rows 16-31 -> LDS (scaled) ----
    const float* Kb = la + ((size_t)b * NN + row0) * MM + 4 * tid;
    float kr[RREG][4];
#pragma unroll
    for (int r = 0; r < RREG; ++r) {
        const float4 k4 = *(const float4*)(Kb + (size_t)r * MM);
        kr[r][0] = k4.x * INV_TAU; kr[r][1] = k4.y * INV_TAU;
        kr[r][2] = k4.z * INV_TAU; kr[r][3] = k4.w * INV_TAU;
    }
#pragma unroll
    for (int r = 0; r < RPB - RREG; ++r) {
        float4 k4 = *(const float4*)(Kb + (size_t)(RREG + r) * MM);
        k4.x *= INV_TAU; k4.y *= INV_TAU; k4.z *= INV_TAU; k4.w *= INV_TAU;
        *(float4*)(&klds[r][4 * tid]) = k4;
    }
    __syncthreads();

    float pb1 = 1.0f, pb2 = 1.0f;
    for (int t = 0; t < 10; ++t) {
        pb1 *= B1f; pb2 *= B2f;
        const float bc1 = 1.0f - pb1, bc2 = 1.0f - pb2;

        // ---- row pass: max ----
        const float4 v4 = *(const float4*)(ws + OFF_V + b * MM + 4 * tid);
#pragma unroll
        for (int r = 0; r < RREG; ++r) {
            float m = fmaxf(fmaxf(kr[r][0] + v4.x, kr[r][1] + v4.y),
                            fmaxf(kr[r][2] + v4.z, kr[r][3] + v4.w));
#pragma unroll
            for (int off = 32; off; off >>= 1) m = fmaxf(m, __shfl_xor(m, off, 64));
            if (lane == 0) redm[wave * RPB + r] = m;
        }
#pragma unroll
        for (int r = 0; r < RPB - RREG; ++r) {
            const float4 k4 = *(const float4*)(&klds[r][4 * tid]);
            float m = fmaxf(fmaxf(k4.x + v4.x, k4.y + v4.y),
                            fmaxf(k4.z + v4.z, k4.w + v4.w));
#pragma unroll
            for (int off = 32; off; off >>= 1) m = fmaxf(m, __shfl_xor(m, off, 64));
            if (lane == 0) redm[wave * RPB + RREG + r] = m;
        }
        __syncthreads();
        if (tid < RPB)
            fin[tid] = fmaxf(fmaxf(redm[tid], redm[RPB + tid]),
                             fmaxf(redm[2 * RPB + tid], redm[3 * RPB + tid]));
        __syncthreads();

        // ---- row pass: exp-sum ----
#pragma unroll
        for (int r = 0; r < RREG; ++r) {
            const float Mr = fin[r];
            float s = __expf(kr[r][0] + v4.x - Mr) + __expf(kr[r][1] + v4.y - Mr)
                    + __expf(kr[r][2] + v4.z - Mr) + __expf(kr[r][3] + v4.w - Mr);
#pragma unroll
            for (int off = 32; off; off >>= 1) s += __shfl_xor(s, off, 64);
            if (lane == 0) reds[wave * RPB + r] = s;
        }
#pragma unroll
        for (int r = 0; r < RPB - RREG; ++r) {
            const float4 k4 = *(const float4*)(&klds[r][4 * tid]);
            const float Mr = fin[RREG + r];
            float s = __expf(k4.x + v4.x - Mr) + __expf(k4.y + v4.y - Mr)
                    + __expf(k4.z + v4.z - Mr) + __expf(k4.w + v4.w - Mr);
#pragma unroll
            for (int off = 32; off; off >>= 1) s += __shfl_xor(s, off, 64);
            if (lane == 0) reds[wave * RPB + RREG + r] = s;
        }
        __syncthreads();
        if (tid < RPB) {
            const int r  = tid;
            const int gi = b * NN + row0 + r;
            const float S   = reds[r] + reds[RPB + r] + reds[2 * RPB + r] + reds[3 * RPB + r];
            const float lse = fin[r] + __logf(S);
            const float uo  = ws[OFF_U + gi];
            const float gu  = (log_a[gi] - lse) - uo;
            const float m_  = B1f * ws[OFF_MU + gi] + (1.f - B1f) * gu;
            const float v_  = B2f * ws[OFF_VU + gi] + (1.f - B2f) * gu * gu;
            ws[OFF_MU + gi] = m_;
            ws[OFF_VU + gi] = v_;
            const float un  = uo + LR * (m_ / bc1) / (sqrtf(v_ / bc2) + EPSA);
            ws[OFF_U + gi]  = un;
            su[r] = un;
        }
        __syncthreads();

        // ---- col partials: exact two-pass, r-outer (one b128 per LDS row) ----
        {
            float cm[4];
#pragma unroll
            for (int j = 0; j < 4; ++j) cm[j] = kr[0][j] + su[0];
#pragma unroll
            for (int r = 1; r < RREG; ++r) {
                const float sr = su[r];
                cm[0] = fmaxf(cm[0], kr[r][0] + sr);
                cm[1] = fmaxf(cm[1], kr[r][1] + sr);
                cm[2] = fmaxf(cm[2], kr[r][2] + sr);
                cm[3] = fmaxf(cm[3], kr[r][3] + sr);
            }
#pragma unroll
            for (int r = 0; r < RPB - RREG; ++r) {
                const float4 k4 = *(const float4*)(&klds[r][4 * tid]);
                const float sr = su[RREG + r];
                cm[0] = fmaxf(cm[0], k4.x + sr);
                cm[1] = fmaxf(cm[1], k4.y + sr);
                cm[2] = fmaxf(cm[2], k4.z + sr);
                cm[3] = fmaxf(cm[3], k4.w + sr);
            }
            float cs[4] = {0.f, 0.f, 0.f, 0.f};
#pragma unroll
            for (int r = 0; r < RREG; ++r) {
                const float sr = su[r];
                cs[0] += __expf(kr[r][0] + sr - cm[0]);
                cs[1] += __expf(kr[r][1] + sr - cm[1]);
                cs[2] += __expf(kr[r][2] + sr - cm[2]);
                cs[3] += __expf(kr[r][3] + sr - cm[3]);
            }
#pragma unroll
            for (int r = 0; r < RPB - RREG; ++r) {
                const float4 k4 = *(const float4*)(&klds[r][4 * tid]);
                const float sr = su[RREG + r];
                cs[0] += __expf(k4.x + sr - cm[0]);
                cs[1] += __expf(k4.y + sr - cm[1]);
                cs[2] += __expf(k4.z + sr - cm[2]);
                cs[3] += __expf(k4.w + sr - cm[3]);
            }
            float2* p = part + ((size_t)b * NGRP + g) * MM + 4 * tid;
            p[0] = make_float2(cm[0], cs[0]);
            p[1] = make_float2(cm[1], cs[1]);
            p[2] = make_float2(cm[2], cs[2]);
            p[3] = make_float2(cm[3], cs[3]);
        }
        gbar(cnt, ep);   // all partials visible device-wide

        // ---- combine + Adam v: block (b,g) handles columns g*32..g*32+31 ----
        {
            const int c32 = tid & 31;
            const int q   = tid >> 5;        // 8 chunks of 4 row-groups
            const float2* pp = part + ((size_t)b * NGRP + q * 4) * MM + (g * 32 + c32);
            float Mc = -3.0e38f, Sc = 0.f;
#pragma unroll
            for (int s5 = 0; s5 < 4; ++s5) {
                const float2 pr = pp[(size_t)s5 * MM];
                const float mn = fmaxf(Mc, pr.x);
                Sc = Sc * __expf(Mc - mn) + pr.y * __expf(pr.x - mn);
                Mc = mn;
            }
            red2[q][c32] = make_float2(Mc, Sc);
            __syncthreads();
            if (tid < 32) {
                float M = -3.0e38f, S = 0.f;
#pragma unroll
                for (int q2 = 0; q2 < 8; ++q2) {
                    const float2 pr = red2[q2][tid];
                    const float mn = fmaxf(M, pr.x);
                    S = S * __expf(M - mn) + pr.y * __expf(pr.x - mn);
                    M = mn;
                }
                const int i     = b * MM + g * 32 + tid;
                const float lse = M + __logf(S);
                const float vo  = ws[OFF_V + i];
                const float gv  = (log_b[i] - lse) - vo;
                const float m_  = B1f * ws[OFF_MV + i] + (1.f - B1f) * gv;
                const float v_  = B2f * ws[OFF_VV + i] + (1.f - B2f) * gv * gv;
                ws[OFF_MV + i] = m_;
                ws[OFF_VV + i] = v_;
                ws[OFF_V + i]  = vo + LR * (m_ / bc1) / (sqrtf(v_ / bc2) + EPSA);
            }
        }
        gbar(cnt, ep);   // fresh v visible for next row pass
    }

    // ---- finalize: out = exp(K/tau + u + v), arg-clamped ----
    const float4 vf = *(const float4*)(ws + OFF_V + b * MM + 4 * tid);
    float* ob = out + ((size_t)b * NN + row0) * MM + 4 * tid;
#pragma unroll
    for (int r = 0; r < RREG; ++r) {
        const float uu = su[r];
        float4 o;
        o.x = __expf(fminf(kr[r][0] + uu + vf.x, EXP_CAP));
        o.y = __expf(fminf(kr[r][1] + uu + vf.y, EXP_CAP));
        o.z = __expf(fminf(kr[r][2] + uu + vf.z, EXP_CAP));
        o.w = __expf(fminf(kr[r][3] + uu + vf.w, EXP_CAP));
        *(float4*)(ob + (size_t)r * MM) = o;
    }
#pragma unroll
    for (int r = 0; r < RPB - RREG; ++r) {
        const float4 k4 = *(const float4*)(&klds[r][4 * tid]);
        const float uu = su[RREG + r];
        float4 o;
        o.x = __expf(fminf(k4.x + uu + vf.x, EXP_CAP));
        o.y = __expf(fminf(k4.y + uu + vf.y, EXP_CAP));
        o.z = __expf(fminf(k4.z + uu + vf.z, EXP_CAP));
        o.w = __expf(fminf(k4.w + uu + vf.w, EXP_CAP));
        *(float4*)(ob + (size_t)(RREG + r) * MM) = o;
    }
}

// ============================================================================
// Legacy fallback path (the verified 339 us kernel) — used only if the
// cooperative launch is rejected.
// ============================================================================
__global__ __launch_bounds__(256, 4) void iter_fused(
    const float* __restrict__ la, const float* __restrict__ log_a,
    float* __restrict__ ws, float2* __restrict__ part,
    float bc1, float bc2)
{
    const int slab = blockIdx.x;
    const int b    = blockIdx.y;
    const int row0 = slab * RPB8;
    const int tid  = threadIdx.x;
    const int wave = tid >> 6;
    const int lane = tid & 63;
    __shared__ float redm[4 * RPB8];
    __shared__ float reds[4 * RPB8];
    __shared__ float fin[RPB8];
    __shared__ float su[RPB8];

    const float* Kb = la + ((size_t)b * NN + row0) * MM + 4 * tid;
    float kr[RPB8][4];
#pragma unroll
    for (int r = 0; r < RPB8; ++r) {
        const float4 k4 = *(const float4*)(Kb + (size_t)r * MM);
        kr[r][0] = k4.x * INV_TAU; kr[r][1] = k4.y * INV_TAU;
        kr[r][2] = k4.z * INV_TAU; kr[r][3] = k4.w * INV_TAU;
    }
    const float4 v4 = *(const float4*)(ws + OFF_V + b * MM + 4 * tid);
    const float vj[4] = {v4.x, v4.y, v4.z, v4.w};

    float pm[RPB8];
#pragma unroll
    for (int r = 0; r < RPB8; ++r)
        pm[r] = fmaxf(fmaxf(kr[r][0] + vj[0], kr[r][1] + vj[1]),
                      fmaxf(kr[r][2] + vj[2], kr[r][3] + vj[3]));
#pragma unroll
    for (int off = 32; off; off >>= 1)
#pragma unroll
        for (int r = 0; r < RPB8; ++r)
            pm[r] = fmaxf(pm[r], __shfl_xor(pm[r], off, 64));
    if (lane == 0)
#pragma unroll
        for (int r = 0; r < RPB8; ++r) redm[wave * RPB8 + r] = pm[r];
    __syncthreads();
    if (tid < RPB8)
        fin[tid] = fmaxf(fmaxf(redm[tid], redm[RPB8 + tid]),
                         fmaxf(redm[2 * RPB8 + tid], redm[3 * RPB8 + tid]));
    __syncthreads();
    float Mr[RPB8];
#pragma unroll
    for (int r = 0; r < RPB8; ++r) Mr[r] = fin[r];

    float ps[RPB8];
#pragma unroll
    for (int r = 0; r < RPB8; ++r)
        ps[r] = __expf(kr[r][0] + vj[0] - Mr[r]) + __expf(kr[r][1] + vj[1] - Mr[r])
              + __expf(kr[r][2] + vj[2] - Mr[r]) + __expf(kr[r][3] + vj[3] - Mr[r]);
#pragma unroll
    for (int off = 32; off; off >>= 1)
#pragma unroll
        for (int r = 0; r < RPB8; ++r)
            ps[r] += __shfl_xor(ps[r], off, 64);
    if (lane == 0)
#pragma unroll
        for (int r = 0; r < RPB8; ++r) reds[wave * RPB8 + r] = ps[r];
    __syncthreads();
    if (tid < RPB8) {
        const int r  = tid;
        const int gi = b * NN + row0 + r;
        const float S   = reds[r] + reds[RPB8 + r] + reds[2 * RPB8 + r] + reds[3 * RPB8 + r];
        const float lse = Mr[r] + __logf(S);
        const float uo  = ws[OFF_U + gi];
        const float gu  = (log_a[gi] - lse) - uo;
        const float m_  = B1f * ws[OFF_MU + gi] + (1.f - B1f) * gu;
        const float v_  = B2f * ws[OFF_VU + gi] + (1.f - B2f) * gu * gu;
        ws[OFF_MU + gi] = m_;
        ws[OFF_VU + gi] = v_;
        const float un  = uo + LR * (m_ / bc1) / (sqrtf(v_ / bc2) + EPSA);
        ws[OFF_U + gi]  = un;
        su[r] = un;
    }
    __syncthreads();
    float uu[RPB8];
#pragma unroll
    for (int r = 0; r < RPB8; ++r) uu[r] = su[r];

    float2 out4[4];
#pragma unroll
    for (int j = 0; j < 4; ++j) {
        float m = kr[0][j] + uu[0];
#pragma unroll
        for (int r = 1; r < RPB8; ++r) m = fmaxf(m, kr[r][j] + uu[r]);
        float s = 0.f;
#pragma unroll
        for (int r = 0; r < RPB8; ++r) s += __expf(kr[r][j] + uu[r] - m);
        out4[j] = make_float2(m, s);
    }
    float2* p = part + ((size_t)b * NSLAB + slab) * MM + 4 * tid;
    p[0] = out4[0]; p[1] = out4[1]; p[2] = out4[2]; p[3] = out4[3];
}

__global__ __launch_bounds__(256, 8) void combine_legacy(
    const float* __restrict__ log_b, float* __restrict__ ws,
    const float2* __restrict__ part, float bc1, float bc2)
{
    const int b   = blockIdx.x >> 4;
    const int mg  = blockIdx.x & 15;
    const int tid = threadIdx.x;
    const int c   = tid & 63;
    const int q   = tid >> 6;
    const int m   = mg * 64 + c;
    __shared__ float2 red[4][64];

    const float2* p = part + ((size_t)b * NSLAB + q * 32) * MM + m;
    float M = -3.0e38f, S = 0.f;
#pragma unroll 8
    for (int s = 0; s < 32; ++s) {
        const float2 pr = p[(size_t)s * MM];
        const float mn = fmaxf(M, pr.x);
        S = S * __expf(M - mn) + pr.y * __expf(pr.x - mn);
        M = mn;
    }
    red[q][c] = make_float2(M, S);
    __syncthreads();
    if (q == 0) {
        const float2 a = red[0][c], bb = red[1][c], cc = red[2][c], d = red[3][c];
        const float Mt = fmaxf(fmaxf(a.x, bb.x), fmaxf(cc.x, d.x));
        const float St = a.y * __expf(a.x - Mt) + bb.y * __expf(bb.x - Mt)
                       + cc.y * __expf(cc.x - Mt) + d.y * __expf(d.x - Mt);
        const int i = b * MM + m;
        const float lse = Mt + __logf(St);
        const float vo  = ws[OFF_V + i];
        const float gv  = (log_b[i] - lse) - vo;
        const float m_  = B1f * ws[OFF_MV + i] + (1.f - B1f) * gv;
        const float v_  = B2f * ws[OFF_VV + i] + (1.f - B2f) * gv * gv;
        ws[OFF_MV + i] = m_;
        ws[OFF_VV + i] = v_;
        ws[OFF_V + i]  = vo + LR * (m_ / bc1) / (sqrtf(v_ / bc2) + EPSA);
    }
}

__global__ void finalize_legacy(const float* __restrict__ la, const float* __restrict__ ws,
                                float* __restrict__ out)
{
    const size_t i4 = (size_t)blockIdx.x * 256 + threadIdx.x;
    const size_t e  = i4 * 4;
    const int row = (int)(e >> 10);
    const int b   = row >> 10;
    const int m   = (int)(e & 1023);
    const float uu = ws[OFF_U + row];
    const float4 k4 = ((const float4*)la)[i4];
    const float4 v4 = *(const float4*)(ws + OFF_V + b * MM + m);
    float4 o;
    o.x = __expf(fminf(k4.x * INV_TAU + uu + v4.x, EXP_CAP));
    o.y = __expf(fminf(k4.y * INV_TAU + uu + v4.y, EXP_CAP));
    o.z = __expf(fminf(k4.z * INV_TAU + uu + v4.z, EXP_CAP));
    o.w = __expf(fminf(k4.w * INV_TAU + uu + v4.w, EXP_CAP));
    ((float4*)out)[i4] = o;
}

extern "C" void kernel_launch(void* const* d_in, const int* in_sizes, int n_in,
                              void* d_out, int out_size, void* d_ws, size_t ws_size,
                              hipStream_t stream) {
    const float* la    = (const float*)d_in[0];
    const float* log_a = (const float*)d_in[1];
    const float* log_b = (const float*)d_in[2];
    float*  out  = (float*)d_out;
    float*  ws   = (float*)d_ws;
    float2* part = (float2*)(ws + OFF_PART);

    // Zero Adam state + barrier counter (graph-safe, replay-safe).
    hipMemsetAsync(d_ws, 0, (OFF_CNT + 16) * sizeof(float), stream);

    void* args[] = {(void*)&la, (void*)&log_a, (void*)&log_b,
                    (void*)&ws, (void*)&part, (void*)&out};
    hipError_t err = hipLaunchCooperativeKernel(
        (const void*)sinkhorn_persistent, dim3(NBLK), dim3(256), args, 0, stream);

    if (err != hipSuccess) {
        // Fallback: previous verified multi-kernel path (339 us).
        for (int t = 1; t <= 10; ++t) {
            const float bc1 = 1.0f - powf(B1f, (float)t);
            const float bc2 = 1.0f - powf(B2f, (float)t);
            iter_fused<<<dim3(NSLAB, BB), 256, 0, stream>>>(la, log_a, ws, part, bc1, bc2);
            combine_legacy<<<BB * MM / 256, 256, 0, stream>>>(log_b, ws, part, bc1, bc2);
        }
        finalize_legacy<<<16384, 256, 0, stream>>>(la, ws, out);
    }
}

// Round 6
// 786.168 us; speedup vs baseline: 3.5063x; 1.7697x over previous
//
#include <hip/hip_runtime.h>
#include <cmath>

#define BB 16
#define NN 1024
#define MM 1024

// ---- persistent-kernel geometry ----
// 512 blocks x 256 threads, 3 blocks/CU capacity (LDS 52.5KB, VGPR cap 168).
// K residency: rows 0-19 in VGPRs (80 regs), rows 20-31 in LDS (48 KB).
#define RPB   32           // rows per block
#define RREG  20           // rows kept in registers
#define RLDS  (RPB - RREG) // 12 rows in LDS
#define NGRP  (NN / RPB)   // 32 row-groups per batch
#define NBLK  (BB * NGRP)  // 512 blocks

// ---- legacy (fallback) geometry ----
#define RPB8  8
#define NSLAB (NN / RPB8)  // 128 slabs per batch

static constexpr float INV_TAU = 20.0f;   // 1/0.05
static constexpr float LR   = 0.5f;
static constexpr float B1f  = 0.9f;
static constexpr float B2f  = 0.999f;
static constexpr float EPSA = 1e-8f;
static constexpr float EXP_CAP = 88.0f;   // clamp the exp ARGUMENT (fast-math safe)

// d_ws layout (floats): u v mu vu mv vv | barrier region | part region.
#define OFF_U    0
#define OFF_V    16384
#define OFF_MU   32768
#define OFF_VU   49152
#define OFF_MV   65536
#define OFF_VV   81920
#define OFF_CNT  98304     // int region: 64 group counters (stride 32), root, flag
#define OFF_PART 102400    // float2 region: [BB][NGRP][MM] = 4 MB

#define CNT_ROOT 2048
#define CNT_FLAG 2080

// ---- sc1 (device-coherent, L2-bypass) accessors for SHARED data only ----
__device__ __forceinline__ void st_sc1_f2(float2* p, float mx, float sy) {
    union { float2 f; unsigned long long u; } cv; cv.f = make_float2(mx, sy);
    __hip_atomic_store((unsigned long long*)p, cv.u, __ATOMIC_RELAXED, __HIP_MEMORY_SCOPE_AGENT);
}
__device__ __forceinline__ float2 ld_sc1_f2(const float2* p) {
    union { float2 f; unsigned long long u; } cv;
    cv.u = __hip_atomic_load((unsigned long long*)p, __ATOMIC_RELAXED, __HIP_MEMORY_SCOPE_AGENT);
    return cv.f;
}
__device__ __forceinline__ void st_sc1_f(float* p, float v) {
    union { float f; unsigned u; } cv; cv.f = v;
    __hip_atomic_store((unsigned*)p, cv.u, __ATOMIC_RELAXED, __HIP_MEMORY_SCOPE_AGENT);
}
__device__ __forceinline__ float4 ld_sc1_f4(const float* p) {
    const float2 a = ld_sc1_f2((const float2*)p);
    const float2 b = ld_sc1_f2((const float2*)(p + 2));
    return make_float4(a.x, a.y, b.x, b.y);
}

// ---- fence-free hierarchical grid barrier ----
// Shared data uses sc1 (always at coherence point), so no L2 wb/inv fences are
// needed. Arrival: 8 blocks -> group counter (64 lines), last -> root, last ->
// flag=ep. Everyone spins on the read-only flag. __syncthreads() at entry
// drains each wave's outstanding (sc1) stores before the leader's arrival.
__device__ __forceinline__ void gbar(int* cb, int bid, int& ep) {
    __syncthreads();
    ++ep;
    if (threadIdx.x == 0) {
        asm volatile("s_waitcnt vmcnt(0)" ::: "memory");
        const int old = __hip_atomic_fetch_add(cb + ((bid >> 3) << 5), 1,
                          __ATOMIC_RELAXED, __HIP_MEMORY_SCOPE_AGENT);
        if (old == ep * 8 - 1) {
            const int ro = __hip_atomic_fetch_add(cb + CNT_ROOT, 1,
                             __ATOMIC_RELAXED, __HIP_MEMORY_SCOPE_AGENT);
            if (ro == ep * 64 - 1)
                __hip_atomic_store(cb + CNT_FLAG, ep,
                                   __ATOMIC_RELAXED, __HIP_MEMORY_SCOPE_AGENT);
        }
        while (__hip_atomic_load(cb + CNT_FLAG, __ATOMIC_RELAXED,
                                 __HIP_MEMORY_SCOPE_AGENT) < ep)
            __builtin_amdgcn_s_sleep(2);
    }
    __syncthreads();
}

// ============================================================================
// Persistent kernel. Block (b,g) owns rows g*32..g*32+31 of batch b; thread
// tid owns columns 4*tid..4*tid+3. Rows 0-19 in VGPRs, 20-31 in LDS.
// Shared traffic (partials, v) via sc1; private Adam state via normal ld/st.
// ============================================================================
__global__ __launch_bounds__(256)
__attribute__((amdgpu_waves_per_eu(3, 3)))
void sinkhorn_persistent(
    const float* __restrict__ la, const float* __restrict__ log_a,
    const float* __restrict__ log_b, float* __restrict__ ws,
    float2* __restrict__ part, float* __restrict__ out)
{
    const int bid  = blockIdx.x;
    const int b    = bid >> 5;          // batch
    const int g    = bid & 31;          // row-group AND column-group
    const int row0 = g * RPB;
    const int tid  = threadIdx.x;
    const int wave = tid >> 6;
    const int lane = tid & 63;

    __shared__ float  klds[RLDS][MM];   // rows 20-31, pre-scaled (48 KB)
    __shared__ float  redm[4 * RPB];
    __shared__ float  reds[4 * RPB];
    __shared__ float  fin[RPB];
    __shared__ float  su[RPB];
    __shared__ float2 red2[8][32];

    int* cb = (int*)ws + OFF_CNT;
    int ep = 0;

    // ---- load K slab: rows 0-19 -> registers, rows 20-31 -> LDS (scaled) ----
    const float* Kb = la + ((size_t)b * NN + row0) * MM + 4 * tid;
    float kr[RREG][4];
#pragma unroll
    for (int r = 0; r < RREG; ++r) {
        const float4 k4 = *(const float4*)(Kb + (size_t)r * MM);
        kr[r][0] = k4.x * INV_TAU; kr[r][1] = k4.y * INV_TAU;
        kr[r][2] = k4.z * INV_TAU; kr[r][3] = k4.w * INV_TAU;
    }
#pragma unroll
    for (int r = 0; r < RLDS; ++r) {
        float4 k4 = *(const float4*)(Kb + (size_t)(RREG + r) * MM);
        k4.x *= INV_TAU; k4.y *= INV_TAU; k4.z *= INV_TAU; k4.w *= INV_TAU;
        *(float4*)(&klds[r][4 * tid]) = k4;
    }
    __syncthreads();

    float pb1 = 1.0f, pb2 = 1.0f;
    for (int t = 0; t < 10; ++t) {
        pb1 *= B1f; pb2 *= B2f;
        const float bc1 = 1.0f - pb1, bc2 = 1.0f - pb2;

        // ---- row pass: max ----
        const float4 v4 = ld_sc1_f4(ws + OFF_V + b * MM + 4 * tid);
#pragma unroll
        for (int r = 0; r < RREG; ++r) {
            float m = fmaxf(fmaxf(kr[r][0] + v4.x, kr[r][1] + v4.y),
                            fmaxf(kr[r][2] + v4.z, kr[r][3] + v4.w));
#pragma unroll
            for (int off = 32; off; off >>= 1) m = fmaxf(m, __shfl_xor(m, off, 64));
            if (lane == 0) redm[wave * RPB + r] = m;
        }
#pragma unroll
        for (int r = 0; r < RLDS; ++r) {
            const float4 k4 = *(const float4*)(&klds[r][4 * tid]);
            float m = fmaxf(fmaxf(k4.x + v4.x, k4.y + v4.y),
                            fmaxf(k4.z + v4.z, k4.w + v4.w));
#pragma unroll
            for (int off = 32; off; off >>= 1) m = fmaxf(m, __shfl_xor(m, off, 64));
            if (lane == 0) redm[wave * RPB + RREG + r] = m;
        }
        __syncthreads();
        if (tid < RPB)
            fin[tid] = fmaxf(fmaxf(redm[tid], redm[RPB + tid]),
                             fmaxf(redm[2 * RPB + tid], redm[3 * RPB + tid]));
        __syncthreads();

        // ---- row pass: exp-sum ----
#pragma unroll
        for (int r = 0; r < RREG; ++r) {
            const float Mr = fin[r];
            float s = __expf(kr[r][0] + v4.x - Mr) + __expf(kr[r][1] + v4.y - Mr)
                    + __expf(kr[r][2] + v4.z - Mr) + __expf(kr[r][3] + v4.w - Mr);
#pragma unroll
            for (int off = 32; off; off >>= 1) s += __shfl_xor(s, off, 64);
            if (lane == 0) reds[wave * RPB + r] = s;
        }
#pragma unroll
        for (int r = 0; r < RLDS; ++r) {
            const float4 k4 = *(const float4*)(&klds[r][4 * tid]);
            const float Mr = fin[RREG + r];
            float s = __expf(k4.x + v4.x - Mr) + __expf(k4.y + v4.y - Mr)
                    + __expf(k4.z + v4.z - Mr) + __expf(k4.w + v4.w - Mr);
#pragma unroll
            for (int off = 32; off; off >>= 1) s += __shfl_xor(s, off, 64);
            if (lane == 0) reds[wave * RPB + RREG + r] = s;
        }
        __syncthreads();
        if (tid < RPB) {
            const int r  = tid;
            const int gi = b * NN + row0 + r;
            const float S   = reds[r] + reds[RPB + r] + reds[2 * RPB + r] + reds[3 * RPB + r];
            const float lse = fin[r] + __logf(S);
            const float uo  = ws[OFF_U + gi];                      // private
            const float gu  = (log_a[gi] - lse) - uo;
            const float m_  = B1f * ws[OFF_MU + gi] + (1.f - B1f) * gu;
            const float v_  = B2f * ws[OFF_VU + gi] + (1.f - B2f) * gu * gu;
            ws[OFF_MU + gi] = m_;
            ws[OFF_VU + gi] = v_;
            const float un  = uo + LR * (m_ / bc1) / (sqrtf(v_ / bc2) + EPSA);
            ws[OFF_U + gi]  = un;
            su[r] = un;
        }
        __syncthreads();

        // ---- col partials: exact two-pass over regs + LDS rows ----
        {
            float cm[4];
#pragma unroll
            for (int j = 0; j < 4; ++j) cm[j] = kr[0][j] + su[0];
#pragma unroll
            for (int r = 1; r < RREG; ++r) {
                const float sr = su[r];
                cm[0] = fmaxf(cm[0], kr[r][0] + sr);
                cm[1] = fmaxf(cm[1], kr[r][1] + sr);
                cm[2] = fmaxf(cm[2], kr[r][2] + sr);
                cm[3] = fmaxf(cm[3], kr[r][3] + sr);
            }
#pragma unroll
            for (int r = 0; r < RLDS; ++r) {
                const float4 k4 = *(const float4*)(&klds[r][4 * tid]);
                const float sr = su[RREG + r];
                cm[0] = fmaxf(cm[0], k4.x + sr);
                cm[1] = fmaxf(cm[1], k4.y + sr);
                cm[2] = fmaxf(cm[2], k4.z + sr);
                cm[3] = fmaxf(cm[3], k4.w + sr);
            }
            float cs[4] = {0.f, 0.f, 0.f, 0.f};
#pragma unroll
            for (int r = 0; r < RREG; ++r) {
                const float sr = su[r];
                cs[0] += __expf(kr[r][0] + sr - cm[0]);
                cs[1] += __expf(kr[r][1] + sr - cm[1]);
                cs[2] += __expf(kr[r][2] + sr - cm[2]);
                cs[3] += __expf(kr[r][3] + sr - cm[3]);
            }
#pragma unroll
            for (int r = 0; r < RLDS; ++r) {
                const float4 k4 = *(const float4*)(&klds[r][4 * tid]);
                const float sr = su[RREG + r];
                cs[0] += __expf(k4.x + sr - cm[0]);
                cs[1] += __expf(k4.y + sr - cm[1]);
                cs[2] += __expf(k4.z + sr - cm[2]);
                cs[3] += __expf(k4.w + sr - cm[3]);
            }
            float2* p = part + ((size_t)b * NGRP + g) * MM + 4 * tid;
            st_sc1_f2(p + 0, cm[0], cs[0]);
            st_sc1_f2(p + 1, cm[1], cs[1]);
            st_sc1_f2(p + 2, cm[2], cs[2]);
            st_sc1_f2(p + 3, cm[3], cs[3]);
        }
        gbar(cb, bid, ep);   // all partials at coherence point

        // ---- combine + Adam v: block (b,g) handles columns g*32..g*32+31 ----
        {
            const int c32 = tid & 31;
            const int q   = tid >> 5;        // 8 chunks of 4 row-groups
            const float2* pp = part + ((size_t)b * NGRP + q * 4) * MM + (g * 32 + c32);
            float Mc = -3.0e38f, Sc = 0.f;
#pragma unroll
            for (int s5 = 0; s5 < 4; ++s5) {
                const float2 pr = ld_sc1_f2(pp + (size_t)s5 * MM);
                const float mn = fmaxf(Mc, pr.x);
                Sc = Sc * __expf(Mc - mn) + pr.y * __expf(pr.x - mn);
                Mc = mn;
            }
            red2[q][c32] = make_float2(Mc, Sc);
            __syncthreads();
            if (tid < 32) {
                float M = -3.0e38f, S = 0.f;
#pragma unroll
                for (int q2 = 0; q2 < 8; ++q2) {
                    const float2 pr = red2[q2][tid];
                    const float mn = fmaxf(M, pr.x);
                    S = S * __expf(M - mn) + pr.y * __expf(pr.x - mn);
                    M = mn;
                }
                const int i     = b * MM + g * 32 + tid;
                const float lse = M + __logf(S);
                const float vo  = ws[OFF_V + i];                 // own sc1 line via L3; see store below
                const float gv  = (log_b[i] - lse) - vo;
                const float m_  = B1f * ws[OFF_MV + i] + (1.f - B1f) * gv;  // private
                const float v_  = B2f * ws[OFF_VV + i] + (1.f - B2f) * gv * gv;
                ws[OFF_MV + i] = m_;
                ws[OFF_VV + i] = v_;
                st_sc1_f(ws + OFF_V + i, vo + LR * (m_ / bc1) / (sqrtf(v_ / bc2) + EPSA));
            }
        }
        gbar(cb, bid, ep);   // fresh v at coherence point
    }

    // ---- finalize: out = exp(K/tau + u + v), arg-clamped ----
    const float4 vf = ld_sc1_f4(ws + OFF_V + b * MM + 4 * tid);
    float* ob = out + ((size_t)b * NN + row0) * MM + 4 * tid;
#pragma unroll
    for (int r = 0; r < RREG; ++r) {
        const float uu = su[r];
        float4 o;
        o.x = __expf(fminf(kr[r][0] + uu + vf.x, EXP_CAP));
        o.y = __expf(fminf(kr[r][1] + uu + vf.y, EXP_CAP));
        o.z = __expf(fminf(kr[r][2] + uu + vf.z, EXP_CAP));
        o.w = __expf(fminf(kr[r][3] + uu + vf.w, EXP_CAP));
        *(float4*)(ob + (size_t)r * MM) = o;
    }
#pragma unroll
    for (int r = 0; r < RLDS; ++r) {
        const float4 k4 = *(const float4*)(&klds[r][4 * tid]);
        const float uu = su[RREG + r];
        float4 o;
        o.x = __expf(fminf(k4.x + uu + vf.x, EXP_CAP));
        o.y = __expf(fminf(k4.y + uu + vf.y, EXP_CAP));
        o.z = __expf(fminf(k4.z + uu + vf.z, EXP_CAP));
        o.w = __expf(fminf(k4.w + uu + vf.w, EXP_CAP));
        *(float4*)(ob + (size_t)(RREG + r) * MM) = o;
    }
}

// ============================================================================
// Legacy fallback path (the verified 339 us kernel) — used only if the
// cooperative launch is rejected.
// ============================================================================
__global__ __launch_bounds__(256, 4) void iter_fused(
    const float* __restrict__ la, const float* __restrict__ log_a,
    float* __restrict__ ws, float2* __restrict__ part,
    float bc1, float bc2)
{
    const int slab = blockIdx.x;
    const int b    = blockIdx.y;
    const int row0 = slab * RPB8;
    const int tid  = threadIdx.x;
    const int wave = tid >> 6;
    const int lane = tid & 63;
    __shared__ float redm[4 * RPB8];
    __shared__ float reds[4 * RPB8];
    __shared__ float fin[RPB8];
    __shared__ float su[RPB8];

    const float* Kb = la + ((size_t)b * NN + row0) * MM + 4 * tid;
    float kr[RPB8][4];
#pragma unroll
    for (int r = 0; r < RPB8; ++r) {
        const float4 k4 = *(const float4*)(Kb + (size_t)r * MM);
        kr[r][0] = k4.x * INV_TAU; kr[r][1] = k4.y * INV_TAU;
        kr[r][2] = k4.z * INV_TAU; kr[r][3] = k4.w * INV_TAU;
    }
    const float4 v4 = *(const float4*)(ws + OFF_V + b * MM + 4 * tid);
    const float vj[4] = {v4.x, v4.y, v4.z, v4.w};

    float pm[RPB8];
#pragma unroll
    for (int r = 0; r < RPB8; ++r)
        pm[r] = fmaxf(fmaxf(kr[r][0] + vj[0], kr[r][1] + vj[1]),
                      fmaxf(kr[r][2] + vj[2], kr[r][3] + vj[3]));
#pragma unroll
    for (int off = 32; off; off >>= 1)
#pragma unroll
        for (int r = 0; r < RPB8; ++r)
            pm[r] = fmaxf(pm[r], __shfl_xor(pm[r], off, 64));
    if (lane == 0)
#pragma unroll
        for (int r = 0; r < RPB8; ++r) redm[wave * RPB8 + r] = pm[r];
    __syncthreads();
    if (tid < RPB8)
        fin[tid] = fmaxf(fmaxf(redm[tid], redm[RPB8 + tid]),
                         fmaxf(redm[2 * RPB8 + tid], redm[3 * RPB8 + tid]));
    __syncthreads();
    float Mr[RPB8];
#pragma unroll
    for (int r = 0; r < RPB8; ++r) Mr[r] = fin[r];

    float ps[RPB8];
#pragma unroll
    for (int r = 0; r < RPB8; ++r)
        ps[r] = __expf(kr[r][0] + vj[0] - Mr[r]) + __expf(kr[r][1] + vj[1] - Mr[r])
              + __expf(kr[r][2] + vj[2] - Mr[r]) + __expf(kr[r][3] + vj[3] - Mr[r]);
#pragma unroll
    for (int off = 32; off; off >>= 1)
#pragma unroll
        for (int r = 0; r < RPB8; ++r)
            ps[r] += __shfl_xor(ps[r], off, 64);
    if (lane == 0)
#pragma unroll
        for (int r = 0; r < RPB8; ++r) reds[wave * RPB8 + r] = ps[r];
    __syncthreads();
    if (tid < RPB8) {
        const int r  = tid;
        const int gi = b * NN + row0 + r;
        const float S   = reds[r] + reds[RPB8 + r] + reds[2 * RPB8 + r] + reds[3 * RPB8 + r];
        const float lse = Mr[r] + __logf(S);
        const float uo  = ws[OFF_U + gi];
        const float gu  = (log_a[gi] - lse) - uo;
        const float m_  = B1f * ws[OFF_MU + gi] + (1.f - B1f) * gu;
        const float v_  = B2f * ws[OFF_VU + gi] + (1.f - B2f) * gu * gu;
        ws[OFF_MU + gi] = m_;
        ws[OFF_VU + gi] = v_;
        const float un  = uo + LR * (m_ / bc1) / (sqrtf(v_ / bc2) + EPSA);
        ws[OFF_U + gi]  = un;
        su[r] = un;
    }
    __syncthreads();
    float uu[RPB8];
#pragma unroll
    for (int r = 0; r < RPB8; ++r) uu[r] = su[r];

    float2 out4[4];
#pragma unroll
    for (int j = 0; j < 4; ++j) {
        float m = kr[0][j] + uu[0];
#pragma unroll
        for (int r = 1; r < RPB8; ++r) m = fmaxf(m, kr[r][j] + uu[r]);
        float s = 0.f;
#pragma unroll
        for (int r = 0; r < RPB8; ++r) s += __expf(kr[r][j] + uu[r] - m);
        out4[j] = make_float2(m, s);
    }
    float2* p = part + ((size_t)b * NSLAB + slab) * MM + 4 * tid;
    p[0] = out4[0]; p[1] = out4[1]; p[2] = out4[2]; p[3] = out4[3];
}

__global__ __launch_bounds__(256, 8) void combine_legacy(
    const float* __restrict__ log_b, float* __restrict__ ws,
    const float2* __restrict__ part, float bc1, float bc2)
{
    const int b   = blockIdx.x >> 4;
    const int mg  = blockIdx.x & 15;
    const int tid = threadIdx.x;
    const int c   = tid & 63;
    const int q   = tid >> 6;
    const int m   = mg * 64 + c;
    __shared__ float2 red[4][64];

    const float2* p = part + ((size_t)b * NSLAB + q * 32) * MM + m;
    float M = -3.0e38f, S = 0.f;
#pragma unroll 8
    for (int s = 0; s < 32; ++s) {
        const float2 pr = p[(size_t)s * MM];
        const float mn = fmaxf(M, pr.x);
        S = S * __expf(M - mn) + pr.y * __expf(pr.x - mn);
        M = mn;
    }
    red[q][c] = make_float2(M, S);
    __syncthreads();
    if (q == 0) {
        const float2 a = red[0][c], bb = red[1][c], cc = red[2][c], d = red[3][c];
        const float Mt = fmaxf(fmaxf(a.x, bb.x), fmaxf(cc.x, d.x));
        const float St = a.y * __expf(a.x - Mt) + bb.y * __expf(bb.x - Mt)
                       + cc.y * __expf(cc.x - Mt) + d.y * __expf(d.x - Mt);
        const int i = b * MM + m;
        const float lse = Mt + __logf(St);
        const float vo  = ws[OFF_V + i];
        const float gv  = (log_b[i] - lse) - vo;
        const float m_  = B1f * ws[OFF_MV + i] + (1.f - B1f) * gv;
        const float v_  = B2f * ws[OFF_VV + i] + (1.f - B2f) * gv * gv;
        ws[OFF_MV + i] = m_;
        ws[OFF_VV + i] = v_;
        ws[OFF_V + i]  = vo + LR * (m_ / bc1) / (sqrtf(v_ / bc2) + EPSA);
    }
}

__global__ void finalize_legacy(const float* __restrict__ la, const float* __restrict__ ws,
                                float* __restrict__ out)
{
    const size_t i4 = (size_t)blockIdx.x * 256 + threadIdx.x;
    const size_t e  = i4 * 4;
    const int row = (int)(e >> 10);
    const int b   = row >> 10;
    const int m   = (int)(e & 1023);
    const float uu = ws[OFF_U + row];
    const float4 k4 = ((const float4*)la)[i4];
    const float4 v4 = *(const float4*)(ws + OFF_V + b * MM + m);
    float4 o;
    o.x = __expf(fminf(k4.x * INV_TAU + uu + v4.x, EXP_CAP));
    o.y = __expf(fminf(k4.y * INV_TAU + uu + v4.y, EXP_CAP));
    o.z = __expf(fminf(k4.z * INV_TAU + uu + v4.z, EXP_CAP));
    o.w = __expf(fminf(k4.w * INV_TAU + uu + v4.w, EXP_CAP));
    ((float4*)out)[i4] = o;
}

extern "C" void kernel_launch(void* const* d_in, const int* in_sizes, int n_in,
                              void* d_out, int out_size, void* d_ws, size_t ws_size,
                              hipStream_t stream) {
    const float* la    = (const float*)d_in[0];
    const float* log_a = (const float*)d_in[1];
    const float* log_b = (const float*)d_in[2];
    float*  out  = (float*)d_out;
    float*  ws   = (float*)d_ws;
    float2* part = (float2*)(ws + OFF_PART);

    // Zero Adam state + barrier region (graph-safe, replay-safe).
    hipMemsetAsync(d_ws, 0, OFF_PART * sizeof(float), stream);

    void* args[] = {(void*)&la, (void*)&log_a, (void*)&log_b,
                    (void*)&ws, (void*)&part, (void*)&out};
    hipError_t err = hipLaunchCooperativeKernel(
        (const void*)sinkhorn_persistent, dim3(NBLK), dim3(256), args, 0, stream);

    if (err != hipSuccess) {
        // Fallback: previous verified multi-kernel path (339 us).
        for (int t = 1; t <= 10; ++t) {
            const float bc1 = 1.0f - powf(B1f, (float)t);
            const float bc2 = 1.0f - powf(B2f, (float)t);
            iter_fused<<<dim3(NSLAB, BB), 256, 0, stream>>>(la, log_a, ws, part, bc1, bc2);
            combine_legacy<<<BB * MM / 256, 256, 0, stream>>>(log_b, ws, part, bc1, bc2);
        }
        finalize_legacy<<<16384, 256, 0, stream>>>(la, ws, out);
    }
}

// Round 7
// 418.462 us; speedup vs baseline: 6.5873x; 1.8787x over previous
//
#include <hip/hip_runtime.h>
#include <cmath>

#define BB 16
#define NN 1024
#define MM 1024

// ---- persistent-kernel geometry ----
// 512 blocks x 256 threads, 2 blocks/CU. Empirical allocator law (R2/R3/R6):
// granted VGPR = 512/(2*waves_min). waves_per_eu(2,2) => 128 granted.
// Demand: kr[16][4]=64 + ~50 working = ~114 <= 128 -> spill-free (R5-verified).
// K residency: rows 0-15 in VGPRs, rows 16-31 in LDS (64 KB).
#define RPB   32           // rows per block
#define RREG  16           // rows kept in registers
#define RLDS  (RPB - RREG) // 16 rows in LDS
#define NGRP  (NN / RPB)   // 32 row-groups per batch
#define NBLK  (BB * NGRP)  // 512 blocks

// ---- legacy (fallback) geometry ----
#define RPB8  8
#define NSLAB (NN / RPB8)  // 128 slabs per batch

static constexpr float INV_TAU = 20.0f;   // 1/0.05
static constexpr float LR   = 0.5f;
static constexpr float B1f  = 0.9f;
static constexpr float B2f  = 0.999f;
static constexpr float EPSA = 1e-8f;
static constexpr float EXP_CAP = 88.0f;   // clamp the exp ARGUMENT (fast-math safe)

// d_ws layout (floats): u v mu vu mv vv | barrier region | part region.
#define OFF_U    0
#define OFF_V    16384
#define OFF_MU   32768
#define OFF_VU   49152
#define OFF_MV   65536
#define OFF_VV   81920
#define OFF_CNT  98304     // int region: 64 group counters (stride 32), root, flag
#define OFF_PART 102400    // float2 region: [BB][NGRP][MM] = 4 MB

#define CNT_ROOT 2048
#define CNT_FLAG 2080

// ---- sc1 (device-coherent) accessors for SHARED data only ----
__device__ __forceinline__ void st_sc1_f2(float2* p, float mx, float sy) {
    union { float2 f; unsigned long long u; } cv; cv.f = make_float2(mx, sy);
    __hip_atomic_store((unsigned long long*)p, cv.u, __ATOMIC_RELAXED, __HIP_MEMORY_SCOPE_AGENT);
}
__device__ __forceinline__ float2 ld_sc1_f2(const float2* p) {
    union { float2 f; unsigned long long u; } cv;
    cv.u = __hip_atomic_load((unsigned long long*)p, __ATOMIC_RELAXED, __HIP_MEMORY_SCOPE_AGENT);
    return cv.f;
}
__device__ __forceinline__ void st_sc1_f(float* p, float v) {
    union { float f; unsigned u; } cv; cv.f = v;
    __hip_atomic_store((unsigned*)p, cv.u, __ATOMIC_RELAXED, __HIP_MEMORY_SCOPE_AGENT);
}
__device__ __forceinline__ float4 ld_sc1_f4(const float* p) {
    const float2 a = ld_sc1_f2((const float2*)p);
    const float2 b = ld_sc1_f2((const float2*)(p + 2));
    return make_float4(a.x, a.y, b.x, b.y);
}

// ---- fence-free hierarchical grid barrier (verified in R6) ----
__device__ __forceinline__ void gbar(int* cb, int bid, int& ep) {
    __syncthreads();
    ++ep;
    if (threadIdx.x == 0) {
        asm volatile("s_waitcnt vmcnt(0)" ::: "memory");
        const int old = __hip_atomic_fetch_add(cb + ((bid >> 3) << 5), 1,
                          __ATOMIC_RELAXED, __HIP_MEMORY_SCOPE_AGENT);
        if (old == ep * 8 - 1) {
            const int ro = __hip_atomic_fetch_add(cb + CNT_ROOT, 1,
                             __ATOMIC_RELAXED, __HIP_MEMORY_SCOPE_AGENT);
            if (ro == ep * 64 - 1)
                __hip_atomic_store(cb + CNT_FLAG, ep,
                                   __ATOMIC_RELAXED, __HIP_MEMORY_SCOPE_AGENT);
        }
        while (__hip_atomic_load(cb + CNT_FLAG, __ATOMIC_RELAXED,
                                 __HIP_MEMORY_SCOPE_AGENT) < ep)
            __builtin_amdgcn_s_sleep(2);
    }
    __syncthreads();
}

// ============================================================================
// Persistent kernel. Block (b,g) owns rows g*32..g*32+31 of batch b; thread
// tid owns columns 4*tid..4*tid+3. Rows 0-15 in VGPRs, 16-31 in LDS.
// Shared traffic (partials, v) via sc1; private Adam state via normal ld/st.
// ============================================================================
__global__ __launch_bounds__(256)
__attribute__((amdgpu_waves_per_eu(2, 2)))
void sinkhorn_persistent(
    const float* __restrict__ la, const float* __restrict__ log_a,
    const float* __restrict__ log_b, float* __restrict__ ws,
    float2* __restrict__ part, float* __restrict__ out)
{
    const int bid  = blockIdx.x;
    const int b    = bid >> 5;          // batch
    const int g    = bid & 31;          // row-group AND column-group
    const int row0 = g * RPB;
    const int tid  = threadIdx.x;
    const int wave = tid >> 6;
    const int lane = tid & 63;

    __shared__ float  klds[RLDS][MM];   // rows 16-31, pre-scaled (64 KB)
    __shared__ float  redm[4 * RPB];
    __shared__ float  reds[4 * RPB];
    __shared__ float  fin[RPB];
    __shared__ float  su[RPB];
    __shared__ float2 red2[8][32];

    int* cb = (int*)ws + OFF_CNT;
    int ep = 0;

    // ---- load K slab: rows 0-15 -> registers, rows 16-31 -> LDS (scaled) ----
    const float* Kb = la + ((size_t)b * NN + row0) * MM + 4 * tid;
    float kr[RREG][4];
#pragma unroll
    for (int r = 0; r < RREG; ++r) {
        const float4 k4 = *(const float4*)(Kb + (size_t)r * MM);
        kr[r][0] = k4.x * INV_TAU; kr[r][1] = k4.y * INV_TAU;
        kr[r][2] = k4.z * INV_TAU; kr[r][3] = k4.w * INV_TAU;
    }
#pragma unroll
    for (int r = 0; r < RLDS; ++r) {
        float4 k4 = *(const float4*)(Kb + (size_t)(RREG + r) * MM);
        k4.x *= INV_TAU; k4.y *= INV_TAU; k4.z *= INV_TAU; k4.w *= INV_TAU;
        *(float4*)(&klds[r][4 * tid]) = k4;
    }
    __syncthreads();

    float pb1 = 1.0f, pb2 = 1.0f;
    for (int t = 0; t < 10; ++t) {
        pb1 *= B1f; pb2 *= B2f;
        const float bc1 = 1.0f - pb1, bc2 = 1.0f - pb2;

        // ---- row pass: max ----
        const float4 v4 = ld_sc1_f4(ws + OFF_V + b * MM + 4 * tid);
#pragma unroll
        for (int r = 0; r < RREG; ++r) {
            float m = fmaxf(fmaxf(kr[r][0] + v4.x, kr[r][1] + v4.y),
                            fmaxf(kr[r][2] + v4.z, kr[r][3] + v4.w));
#pragma unroll
            for (int off = 32; off; off >>= 1) m = fmaxf(m, __shfl_xor(m, off, 64));
            if (lane == 0) redm[wave * RPB + r] = m;
        }
#pragma unroll
        for (int r = 0; r < RLDS; ++r) {
            const float4 k4 = *(const float4*)(&klds[r][4 * tid]);
            float m = fmaxf(fmaxf(k4.x + v4.x, k4.y + v4.y),
                            fmaxf(k4.z + v4.z, k4.w + v4.w));
#pragma unroll
            for (int off = 32; off; off >>= 1) m = fmaxf(m, __shfl_xor(m, off, 64));
            if (lane == 0) redm[wave * RPB + RREG + r] = m;
        }
        __syncthreads();
        if (tid < RPB)
            fin[tid] = fmaxf(fmaxf(redm[tid], redm[RPB + tid]),
                             fmaxf(redm[2 * RPB + tid], redm[3 * RPB + tid]));
        __syncthreads();

        // ---- row pass: exp-sum ----
#pragma unroll
        for (int r = 0; r < RREG; ++r) {
            const float Mr = fin[r];
            float s = __expf(kr[r][0] + v4.x - Mr) + __expf(kr[r][1] + v4.y - Mr)
                    + __expf(kr[r][2] + v4.z - Mr) + __expf(kr[r][3] + v4.w - Mr);
#pragma unroll
            for (int off = 32; off; off >>= 1) s += __shfl_xor(s, off, 64);
            if (lane == 0) reds[wave * RPB + r] = s;
        }
#pragma unroll
        for (int r = 0; r < RLDS; ++r) {
            const float4 k4 = *(const float4*)(&klds[r][4 * tid]);
            const float Mr = fin[RREG + r];
            float s = __expf(k4.x + v4.x - Mr) + __expf(k4.y + v4.y - Mr)
                    + __expf(k4.z + v4.z - Mr) + __expf(k4.w + v4.w - Mr);
#pragma unroll
            for (int off = 32; off; off >>= 1) s += __shfl_xor(s, off, 64);
            if (lane == 0) reds[wave * RPB + RREG + r] = s;
        }
        __syncthreads();
        if (tid < RPB) {
            const int r  = tid;
            const int gi = b * NN + row0 + r;
            const float S   = reds[r] + reds[RPB + r] + reds[2 * RPB + r] + reds[3 * RPB + r];
            const float lse = fin[r] + __logf(S);
            const float uo  = ws[OFF_U + gi];                      // private
            const float gu  = (log_a[gi] - lse) - uo;
            const float m_  = B1f * ws[OFF_MU + gi] + (1.f - B1f) * gu;
            const float v_  = B2f * ws[OFF_VU + gi] + (1.f - B2f) * gu * gu;
            ws[OFF_MU + gi] = m_;
            ws[OFF_VU + gi] = v_;
            const float un  = uo + LR * (m_ / bc1) / (sqrtf(v_ / bc2) + EPSA);
            ws[OFF_U + gi]  = un;
            su[r] = un;
        }
        __syncthreads();

        // ---- col partials: exact two-pass over regs + LDS rows ----
        {
            float cm[4];
#pragma unroll
            for (int j = 0; j < 4; ++j) cm[j] = kr[0][j] + su[0];
#pragma unroll
            for (int r = 1; r < RREG; ++r) {
                const float sr = su[r];
                cm[0] = fmaxf(cm[0], kr[r][0] + sr);
                cm[1] = fmaxf(cm[1], kr[r][1] + sr);
                cm[2] = fmaxf(cm[2], kr[r][2] + sr);
                cm[3] = fmaxf(cm[3], kr[r][3] + sr);
            }
#pragma unroll
            for (int r = 0; r < RLDS; ++r) {
                const float4 k4 = *(const float4*)(&klds[r][4 * tid]);
                const float sr = su[RREG + r];
                cm[0] = fmaxf(cm[0], k4.x + sr);
                cm[1] = fmaxf(cm[1], k4.y + sr);
                cm[2] = fmaxf(cm[2], k4.z + sr);
                cm[3] = fmaxf(cm[3], k4.w + sr);
            }
            float cs[4] = {0.f, 0.f, 0.f, 0.f};
#pragma unroll
            for (int r = 0; r < RREG; ++r) {
                const float sr = su[r];
                cs[0] += __expf(kr[r][0] + sr - cm[0]);
                cs[1] += __expf(kr[r][1] + sr - cm[1]);
                cs[2] += __expf(kr[r][2] + sr - cm[2]);
                cs[3] += __expf(kr[r][3] + sr - cm[3]);
            }
#pragma unroll
            for (int r = 0; r < RLDS; ++r) {
                const float4 k4 = *(const float4*)(&klds[r][4 * tid]);
                const float sr = su[RREG + r];
                cs[0] += __expf(k4.x + sr - cm[0]);
                cs[1] += __expf(k4.y + sr - cm[1]);
                cs[2] += __expf(k4.z + sr - cm[2]);
                cs[3] += __expf(k4.w + sr - cm[3]);
            }
            float2* p = part + ((size_t)b * NGRP + g) * MM + 4 * tid;
            st_sc1_f2(p + 0, cm[0], cs[0]);
            st_sc1_f2(p + 1, cm[1], cs[1]);
            st_sc1_f2(p + 2, cm[2], cs[2]);
            st_sc1_f2(p + 3, cm[3], cs[3]);
        }
        gbar(cb, bid, ep);   // all partials at coherence point

        // ---- combine + Adam v: block (b,g) handles columns g*32..g*32+31 ----
        {
            const int c32 = tid & 31;
            const int q   = tid >> 5;        // 8 chunks of 4 row-groups
            const float2* pp = part + ((size_t)b * NGRP + q * 4) * MM + (g * 32 + c32);
            float Mc = -3.0e38f, Sc = 0.f;
#pragma unroll
            for (int s5 = 0; s5 < 4; ++s5) {
                const float2 pr = ld_sc1_f2(pp + (size_t)s5 * MM);
                const float mn = fmaxf(Mc, pr.x);
                Sc = Sc * __expf(Mc - mn) + pr.y * __expf(pr.x - mn);
                Mc = mn;
            }
            red2[q][c32] = make_float2(Mc, Sc);
            __syncthreads();
            if (tid < 32) {
                float M = -3.0e38f, S = 0.f;
#pragma unroll
                for (int q2 = 0; q2 < 8; ++q2) {
                    const float2 pr = red2[q2][tid];
                    const float mn = fmaxf(M, pr.x);
                    S = S * __expf(M - mn) + pr.y * __expf(pr.x - mn);
                    M = mn;
                }
                const int i     = b * MM + g * 32 + tid;
                const float lse = M + __logf(S);
                const float vo  = ws[OFF_V + i];
                const float gv  = (log_b[i] - lse) - vo;
                const float m_  = B1f * ws[OFF_MV + i] + (1.f - B1f) * gv;  // private
                const float v_  = B2f * ws[OFF_VV + i] + (1.f - B2f) * gv * gv;
                ws[OFF_MV + i] = m_;
                ws[OFF_VV + i] = v_;
                st_sc1_f(ws + OFF_V + i, vo + LR * (m_ / bc1) / (sqrtf(v_ / bc2) + EPSA));
            }
        }
        gbar(cb, bid, ep);   // fresh v at coherence point
    }

    // ---- finalize: out = exp(K/tau + u + v), arg-clamped ----
    const float4 vf = ld_sc1_f4(ws + OFF_V + b * MM + 4 * tid);
    float* ob = out + ((size_t)b * NN + row0) * MM + 4 * tid;
#pragma unroll
    for (int r = 0; r < RREG; ++r) {
        const float uu = su[r];
        float4 o;
        o.x = __expf(fminf(kr[r][0] + uu + vf.x, EXP_CAP));
        o.y = __expf(fminf(kr[r][1] + uu + vf.y, EXP_CAP));
        o.z = __expf(fminf(kr[r][2] + uu + vf.z, EXP_CAP));
        o.w = __expf(fminf(kr[r][3] + uu + vf.w, EXP_CAP));
        *(float4*)(ob + (size_t)r * MM) = o;
    }
#pragma unroll
    for (int r = 0; r < RLDS; ++r) {
        const float4 k4 = *(const float4*)(&klds[r][4 * tid]);
        const float uu = su[RREG + r];
        float4 o;
        o.x = __expf(fminf(k4.x + uu + vf.x, EXP_CAP));
        o.y = __expf(fminf(k4.y + uu + vf.y, EXP_CAP));
        o.z = __expf(fminf(k4.z + uu + vf.z, EXP_CAP));
        o.w = __expf(fminf(k4.w + uu + vf.w, EXP_CAP));
        *(float4*)(ob + (size_t)(RREG + r) * MM) = o;
    }
}

// ============================================================================
// Legacy fallback path (the verified 339 us kernel) — used only if the
// cooperative launch is rejected.
// ============================================================================
__global__ __launch_bounds__(256, 4) void iter_fused(
    const float* __restrict__ la, const float* __restrict__ log_a,
    float* __restrict__ ws, float2* __restrict__ part,
    float bc1, float bc2)
{
    const int slab = blockIdx.x;
    const int b    = blockIdx.y;
    const int row0 = slab * RPB8;
    const int tid  = threadIdx.x;
    const int wave = tid >> 6;
    const int lane = tid & 63;
    __shared__ float redm[4 * RPB8];
    __shared__ float reds[4 * RPB8];
    __shared__ float fin[RPB8];
    __shared__ float su[RPB8];

    const float* Kb = la + ((size_t)b * NN + row0) * MM + 4 * tid;
    float kr[RPB8][4];
#pragma unroll
    for (int r = 0; r < RPB8; ++r) {
        const float4 k4 = *(const float4*)(Kb + (size_t)r * MM);
        kr[r][0] = k4.x * INV_TAU; kr[r][1] = k4.y * INV_TAU;
        kr[r][2] = k4.z * INV_TAU; kr[r][3] = k4.w * INV_TAU;
    }
    const float4 v4 = *(const float4*)(ws + OFF_V + b * MM + 4 * tid);
    const float vj[4] = {v4.x, v4.y, v4.z, v4.w};

    float pm[RPB8];
#pragma unroll
    for (int r = 0; r < RPB8; ++r)
        pm[r] = fmaxf(fmaxf(kr[r][0] + vj[0], kr[r][1] + vj[1]),
                      fmaxf(kr[r][2] + vj[2], kr[r][3] + vj[3]));
#pragma unroll
    for (int off = 32; off; off >>= 1)
#pragma unroll
        for (int r = 0; r < RPB8; ++r)
            pm[r] = fmaxf(pm[r], __shfl_xor(pm[r], off, 64));
    if (lane == 0)
#pragma unroll
        for (int r = 0; r < RPB8; ++r) redm[wave * RPB8 + r] = pm[r];
    __syncthreads();
    if (tid < RPB8)
        fin[tid] = fmaxf(fmaxf(redm[tid], redm[RPB8 + tid]),
                         fmaxf(redm[2 * RPB8 + tid], redm[3 * RPB8 + tid]));
    __syncthreads();
    float Mr[RPB8];
#pragma unroll
    for (int r = 0; r < RPB8; ++r) Mr[r] = fin[r];

    float ps[RPB8];
#pragma unroll
    for (int r = 0; r < RPB8; ++r)
        ps[r] = __expf(kr[r][0] + vj[0] - Mr[r]) + __expf(kr[r][1] + vj[1] - Mr[r])
              + __expf(kr[r][2] + vj[2] - Mr[r]) + __expf(kr[r][3] + vj[3] - Mr[r]);
#pragma unroll
    for (int off = 32; off; off >>= 1)
#pragma unroll
        for (int r = 0; r < RPB8; ++r)
            ps[r] += __shfl_xor(ps[r], off, 64);
    if (lane == 0)
#pragma unroll
        for (int r = 0; r < RPB8; ++r) reds[wave * RPB8 + r] = ps[r];
    __syncthreads();
    if (tid < RPB8) {
        const int r  = tid;
        const int gi = b * NN + row0 + r;
        const float S   = reds[r] + reds[RPB8 + r] + reds[2 * RPB8 + r] + reds[3 * RPB8 + r];
        const float lse = Mr[r] + __logf(S);
        const float uo  = ws[OFF_U + gi];
        const float gu  = (log_a[gi] - lse) - uo;
        const float m_  = B1f * ws[OFF_MU + gi] + (1.f - B1f) * gu;
        const float v_  = B2f * ws[OFF_VU + gi] + (1.f - B2f) * gu * gu;
        ws[OFF_MU + gi] = m_;
        ws[OFF_VU + gi] = v_;
        const float un  = uo + LR * (m_ / bc1) / (sqrtf(v_ / bc2) + EPSA);
        ws[OFF_U + gi]  = un;
        su[r] = un;
    }
    __syncthreads();
    float uu[RPB8];
#pragma unroll
    for (int r = 0; r < RPB8; ++r) uu[r] = su[r];

    float2 out4[4];
#pragma unroll
    for (int j = 0; j < 4; ++j) {
        float m = kr[0][j] + uu[0];
#pragma unroll
        for (int r = 1; r < RPB8; ++r) m = fmaxf(m, kr[r][j] + uu[r]);
        float s = 0.f;
#pragma unroll
        for (int r = 0; r < RPB8; ++r) s += __expf(kr[r][j] + uu[r] - m);
        out4[j] = make_float2(m, s);
    }
    float2* p = part + ((size_t)b * NSLAB + slab) * MM + 4 * tid;
    p[0] = out4[0]; p[1] = out4[1]; p[2] = out4[2]; p[3] = out4[3];
}

__global__ __launch_bounds__(256, 8) void combine_legacy(
    const float* __restrict__ log_b, float* __restrict__ ws,
    const float2* __restrict__ part, float bc1, float bc2)
{
    const int b   = blockIdx.x >> 4;
    const int mg  = blockIdx.x & 15;
    const int tid = threadIdx.x;
    const int c   = tid & 63;
    const int q   = tid >> 6;
    const int m   = mg * 64 + c;
    __shared__ float2 red[4][64];

    const float2* p = part + ((size_t)b * NSLAB + q * 32) * MM + m;
    float M = -3.0e38f, S = 0.f;
#pragma unroll 8
    for (int s = 0; s < 32; ++s) {
        const float2 pr = p[(size_t)s * MM];
        const float mn = fmaxf(M, pr.x);
        S = S * __expf(M - mn) + pr.y * __expf(pr.x - mn);
        M = mn;
    }
    red[q][c] = make_float2(M, S);
    __syncthreads();
    if (q == 0) {
        const float2 a = red[0][c], bb = red[1][c], cc = red[2][c], d = red[3][c];
        const float Mt = fmaxf(fmaxf(a.x, bb.x), fmaxf(cc.x, d.x));
        const float St = a.y * __expf(a.x - Mt) + bb.y * __expf(bb.x - Mt)
                       + cc.y * __expf(cc.x - Mt) + d.y * __expf(d.x - Mt);
        const int i = b * MM + m;
        const float lse = Mt + __logf(St);
        const float vo  = ws[OFF_V + i];
        const float gv  = (log_b[i] - lse) - vo;
        const float m_  = B1f * ws[OFF_MV + i] + (1.f - B1f) * gv;
        const float v_  = B2f * ws[OFF_VV + i] + (1.f - B2f) * gv * gv;
        ws[OFF_MV + i] = m_;
        ws[OFF_VV + i] = v_;
        ws[OFF_V + i]  = vo + LR * (m_ / bc1) / (sqrtf(v_ / bc2) + EPSA);
    }
}

__global__ void finalize_legacy(const float* __restrict__ la, const float* __restrict__ ws,
                                float* __restrict__ out)
{
    const size_t i4 = (size_t)blockIdx.x * 256 + threadIdx.x;
    const size_t e  = i4 * 4;
    const int row = (int)(e >> 10);
    const int b   = row >> 10;
    const int m   = (int)(e & 1023);
    const float uu = ws[OFF_U + row];
    const float4 k4 = ((const float4*)la)[i4];
    const float4 v4 = *(const float4*)(ws + OFF_V + b * MM + m);
    float4 o;
    o.x = __expf(fminf(k4.x * INV_TAU + uu + v4.x, EXP_CAP));
    o.y = __expf(fminf(k4.y * INV_TAU + uu + v4.y, EXP_CAP));
    o.z = __expf(fminf(k4.z * INV_TAU + uu + v4.z, EXP_CAP));
    o.w = __expf(fminf(k4.w * INV_TAU + uu + v4.w, EXP_CAP));
    ((float4*)out)[i4] = o;
}

extern "C" void kernel_launch(void* const* d_in, const int* in_sizes, int n_in,
                              void* d_out, int out_size, void* d_ws, size_t ws_size,
                              hipStream_t stream) {
    const float* la    = (const float*)d_in[0];
    const float* log_a = (const float*)d_in[1];
    const float* log_b = (const float*)d_in[2];
    float*  out  = (float*)d_out;
    float*  ws   = (float*)d_ws;
    float2* part = (float2*)(ws + OFF_PART);

    // Zero Adam state + barrier region (graph-safe, replay-safe).
    hipMemsetAsync(d_ws, 0, OFF_PART * sizeof(float), stream);

    void* args[] = {(void*)&la, (void*)&log_a, (void*)&log_b,
                    (void*)&ws, (void*)&part, (void*)&out};
    hipError_t err = hipLaunchCooperativeKernel(
        (const void*)sinkhorn_persistent, dim3(NBLK), dim3(256), args, 0, stream);

    if (err != hipSuccess) {
        // Fallback: previous verified multi-kernel path (339 us).
        for (int t = 1; t <= 10; ++t) {
            const float bc1 = 1.0f - powf(B1f, (float)t);
            const float bc2 = 1.0f - powf(B2f, (float)t);
            iter_fused<<<dim3(NSLAB, BB), 256, 0, stream>>>(la, log_a, ws, part, bc1, bc2);
            combine_legacy<<<BB * MM / 256, 256, 0, stream>>>(log_b, ws, part, bc1, bc2);
        }
        finalize_legacy<<<16384, 256, 0, stream>>>(la, ws, out);
    }
}

// Round 8
// 386.130 us; speedup vs baseline: 7.1389x; 1.0837x over previous
//
#include <hip/hip_runtime.h>
#include <cmath>

#define BB 16
#define NN 1024
#define MM 1024

// ---- persistent-kernel geometry ----
// 512 blocks x 256 threads, 2 blocks/CU. Empirical allocator law (R2/R3/R6):
// granted VGPR = 512/(2*waves_min). waves_per_eu(2,2) => 128 granted.
// Demand: kr[16][4]=64 + ~50 working = ~114 <= 128 -> spill-free (R5/R7-verified).
// K residency: rows 0-15 in VGPRs, rows 16-31 in LDS (64 KB).
#define RPB   32           // rows per block
#define RREG  16           // rows kept in registers
#define RLDS  (RPB - RREG) // 16 rows in LDS
#define NGRP  (NN / RPB)   // 32 row-groups per batch
#define NBLK  (BB * NGRP)  // 512 blocks

// ---- legacy (fallback) geometry ----
#define RPB8  8
#define NSLAB (NN / RPB8)  // 128 slabs per batch

static constexpr float INV_TAU = 20.0f;   // 1/0.05
static constexpr float LR   = 0.5f;
static constexpr float B1f  = 0.9f;
static constexpr float B2f  = 0.999f;
static constexpr float EPSA = 1e-8f;
static constexpr float EXP_CAP = 88.0f;   // clamp the exp ARGUMENT (fast-math safe)

// d_ws layout (floats): u v mu vu mv vv | barrier region | part region.
#define OFF_U    0
#define OFF_V    16384
#define OFF_MU   32768
#define OFF_VU   49152
#define OFF_MV   65536
#define OFF_VV   81920
#define OFF_CNT  98304     // int region: slots[16][64] then flags[16*32]
#define OFF_PART 102400    // float2 region: [BB][NGRP][MM] = 4 MB

#define FLAG_BASE 1024     // int offset of flags within barrier region

// ---- sc1 (device-coherent) accessors for SHARED data only ----
__device__ __forceinline__ void st_sc1_f2(float2* p, float mx, float sy) {
    union { float2 f; unsigned long long u; } cv; cv.f = make_float2(mx, sy);
    __hip_atomic_store((unsigned long long*)p, cv.u, __ATOMIC_RELAXED, __HIP_MEMORY_SCOPE_AGENT);
}
__device__ __forceinline__ float2 ld_sc1_f2(const float2* p) {
    union { float2 f; unsigned long long u; } cv;
    cv.u = __hip_atomic_load((unsigned long long*)p, __ATOMIC_RELAXED, __HIP_MEMORY_SCOPE_AGENT);
    return cv.f;
}
__device__ __forceinline__ void st_sc1_f(float* p, float v) {
    union { float f; unsigned u; } cv; cv.f = v;
    __hip_atomic_store((unsigned*)p, cv.u, __ATOMIC_RELAXED, __HIP_MEMORY_SCOPE_AGENT);
}
__device__ __forceinline__ float4 ld_sc1_f4(const float* p) {
    const float2 a = ld_sc1_f2((const float2*)p);
    const float2 b = ld_sc1_f2((const float2*)(p + 2));
    return make_float4(a.x, a.y, b.x, b.y);
}

// ---- per-batch barrier: store-slot + lane-parallel poll, ZERO RMWs ----
// Only the 32 blocks of one batch synchronize (all cross-block reads are
// batch-local). Arrival: thread 0 stores slot[b][g]=ep (monotonic). Leader
// block (g==0): wave-0 lanes each poll one slot; __all(slot>=ep) -> store
// flag[b]=ep. Followers spin on the flag. Visibility: every wave drains
// vmcnt(0) before the entry s_barrier (compiler-enforced), so slot/flag
// stores are issued only after all the block's data stores are at the
// coherence point (same argument as the R6/R7 barrier, verified passing).
__device__ __forceinline__ void gbar(int* cb, int b, int g, int& ep) {
    __syncthreads();
    ++ep;
    const int tid = threadIdx.x;
    if (tid == 0)
        __hip_atomic_store(cb + b * 64 + g, ep,
                           __ATOMIC_RELAXED, __HIP_MEMORY_SCOPE_AGENT);
    if (g == 0) {
        if (tid < 64) {   // leader: full wave 0 polls (lane L -> slot L&31)
            for (;;) {
                const int v = __hip_atomic_load(cb + b * 64 + (tid & 31),
                                __ATOMIC_RELAXED, __HIP_MEMORY_SCOPE_AGENT);
                if (__all(v >= ep)) break;
                __builtin_amdgcn_s_sleep(1);
            }
            if (tid == 0)
                __hip_atomic_store(cb + FLAG_BASE + b * 32, ep,
                                   __ATOMIC_RELAXED, __HIP_MEMORY_SCOPE_AGENT);
        }
    } else if (tid == 0) {
        while (__hip_atomic_load(cb + FLAG_BASE + b * 32,
                 __ATOMIC_RELAXED, __HIP_MEMORY_SCOPE_AGENT) < ep)
            __builtin_amdgcn_s_sleep(1);
    }
    __syncthreads();
}

// ============================================================================
// Persistent kernel. Block (b,g) owns rows g*32..g*32+31 of batch b; thread
// tid owns columns 4*tid..4*tid+3. Rows 0-15 in VGPRs, 16-31 in LDS.
// Shared traffic (partials, v) via sc1; private Adam state via normal ld/st.
// ============================================================================
__global__ __launch_bounds__(256)
__attribute__((amdgpu_waves_per_eu(2, 2)))
void sinkhorn_persistent(
    const float* __restrict__ la, const float* __restrict__ log_a,
    const float* __restrict__ log_b, float* __restrict__ ws,
    float2* __restrict__ part, float* __restrict__ out)
{
    const int bid  = blockIdx.x;
    const int b    = bid >> 5;          // batch
    const int g    = bid & 31;          // row-group AND column-group
    const int row0 = g * RPB;
    const int tid  = threadIdx.x;
    const int wave = tid >> 6;
    const int lane = tid & 63;

    __shared__ float  klds[RLDS][MM];   // rows 16-31, pre-scaled (64 KB)
    __shared__ float  redm[4 * RPB];
    __shared__ float  reds[4 * RPB];
    __shared__ float  fin[RPB];
    __shared__ float  su[RPB];
    __shared__ float2 red2[8][32];

    int* cb = (int*)ws + OFF_CNT;
    int ep = 0;

    // ---- load K slab: rows 0-15 -> registers, rows 16-31 -> LDS (scaled) ----
    const float* Kb = la + ((size_t)b * NN + row0) * MM + 4 * tid;
    float kr[RREG][4];
#pragma unroll
    for (int r = 0; r < RREG; ++r) {
        const float4 k4 = *(const float4*)(Kb + (size_t)r * MM);
        kr[r][0] = k4.x * INV_TAU; kr[r][1] = k4.y * INV_TAU;
        kr[r][2] = k4.z * INV_TAU; kr[r][3] = k4.w * INV_TAU;
    }
#pragma unroll
    for (int r = 0; r < RLDS; ++r) {
        float4 k4 = *(const float4*)(Kb + (size_t)(RREG + r) * MM);
        k4.x *= INV_TAU; k4.y *= INV_TAU; k4.z *= INV_TAU; k4.w *= INV_TAU;
        *(float4*)(&klds[r][4 * tid]) = k4;
    }
    __syncthreads();

    float pb1 = 1.0f, pb2 = 1.0f;
    for (int t = 0; t < 10; ++t) {
        pb1 *= B1f; pb2 *= B2f;
        const float bc1 = 1.0f - pb1, bc2 = 1.0f - pb2;

        // ---- row pass: max ----
        const float4 v4 = ld_sc1_f4(ws + OFF_V + b * MM + 4 * tid);
#pragma unroll
        for (int r = 0; r < RREG; ++r) {
            float m = fmaxf(fmaxf(kr[r][0] + v4.x, kr[r][1] + v4.y),
                            fmaxf(kr[r][2] + v4.z, kr[r][3] + v4.w));
#pragma unroll
            for (int off = 32; off; off >>= 1) m = fmaxf(m, __shfl_xor(m, off, 64));
            if (lane == 0) redm[wave * RPB + r] = m;
        }
#pragma unroll
        for (int r = 0; r < RLDS; ++r) {
            const float4 k4 = *(const float4*)(&klds[r][4 * tid]);
            float m = fmaxf(fmaxf(k4.x + v4.x, k4.y + v4.y),
                            fmaxf(k4.z + v4.z, k4.w + v4.w));
#pragma unroll
            for (int off = 32; off; off >>= 1) m = fmaxf(m, __shfl_xor(m, off, 64));
            if (lane == 0) redm[wave * RPB + RREG + r] = m;
        }
        __syncthreads();
        if (tid < RPB)
            fin[tid] = fmaxf(fmaxf(redm[tid], redm[RPB + tid]),
                             fmaxf(redm[2 * RPB + tid], redm[3 * RPB + tid]));
        __syncthreads();

        // ---- row pass: exp-sum ----
#pragma unroll
        for (int r = 0; r < RREG; ++r) {
            const float Mr = fin[r];
            float s = __expf(kr[r][0] + v4.x - Mr) + __expf(kr[r][1] + v4.y - Mr)
                    + __expf(kr[r][2] + v4.z - Mr) + __expf(kr[r][3] + v4.w - Mr);
#pragma unroll
            for (int off = 32; off; off >>= 1) s += __shfl_xor(s, off, 64);
            if (lane == 0) reds[wave * RPB + r] = s;
        }
#pragma unroll
        for (int r = 0; r < RLDS; ++r) {
            const float4 k4 = *(const float4*)(&klds[r][4 * tid]);
            const float Mr = fin[RREG + r];
            float s = __expf(k4.x + v4.x - Mr) + __expf(k4.y + v4.y - Mr)
                    + __expf(k4.z + v4.z - Mr) + __expf(k4.w + v4.w - Mr);
#pragma unroll
            for (int off = 32; off; off >>= 1) s += __shfl_xor(s, off, 64);
            if (lane == 0) reds[wave * RPB + RREG + r] = s;
        }
        __syncthreads();
        if (tid < RPB) {
            const int r  = tid;
            const int gi = b * NN + row0 + r;
            const float S   = reds[r] + reds[RPB + r] + reds[2 * RPB + r] + reds[3 * RPB + r];
            const float lse = fin[r] + __logf(S);
            const float uo  = ws[OFF_U + gi];                      // private
            const float gu  = (log_a[gi] - lse) - uo;
            const float m_  = B1f * ws[OFF_MU + gi] + (1.f - B1f) * gu;
            const float v_  = B2f * ws[OFF_VU + gi] + (1.f - B2f) * gu * gu;
            ws[OFF_MU + gi] = m_;
            ws[OFF_VU + gi] = v_;
            const float un  = uo + LR * (m_ / bc1) / (sqrtf(v_ / bc2) + EPSA);
            ws[OFF_U + gi]  = un;
            su[r] = un;
        }
        __syncthreads();

        // ---- col partials: exact two-pass over regs + LDS rows ----
        {
            float cm[4];
#pragma unroll
            for (int j = 0; j < 4; ++j) cm[j] = kr[0][j] + su[0];
#pragma unroll
            for (int r = 1; r < RREG; ++r) {
                const float sr = su[r];
                cm[0] = fmaxf(cm[0], kr[r][0] + sr);
                cm[1] = fmaxf(cm[1], kr[r][1] + sr);
                cm[2] = fmaxf(cm[2], kr[r][2] + sr);
                cm[3] = fmaxf(cm[3], kr[r][3] + sr);
            }
#pragma unroll
            for (int r = 0; r < RLDS; ++r) {
                const float4 k4 = *(const float4*)(&klds[r][4 * tid]);
                const float sr = su[RREG + r];
                cm[0] = fmaxf(cm[0], k4.x + sr);
                cm[1] = fmaxf(cm[1], k4.y + sr);
                cm[2] = fmaxf(cm[2], k4.z + sr);
                cm[3] = fmaxf(cm[3], k4.w + sr);
            }
            float cs[4] = {0.f, 0.f, 0.f, 0.f};
#pragma unroll
            for (int r = 0; r < RREG; ++r) {
                const float sr = su[r];
                cs[0] += __expf(kr[r][0] + sr - cm[0]);
                cs[1] += __expf(kr[r][1] + sr - cm[1]);
                cs[2] += __expf(kr[r][2] + sr - cm[2]);
                cs[3] += __expf(kr[r][3] + sr - cm[3]);
            }
#pragma unroll
            for (int r = 0; r < RLDS; ++r) {
                const float4 k4 = *(const float4*)(&klds[r][4 * tid]);
                const float sr = su[RREG + r];
                cs[0] += __expf(k4.x + sr - cm[0]);
                cs[1] += __expf(k4.y + sr - cm[1]);
                cs[2] += __expf(k4.z + sr - cm[2]);
                cs[3] += __expf(k4.w + sr - cm[3]);
            }
            float2* p = part + ((size_t)b * NGRP + g) * MM + 4 * tid;
            st_sc1_f2(p + 0, cm[0], cs[0]);
            st_sc1_f2(p + 1, cm[1], cs[1]);
            st_sc1_f2(p + 2, cm[2], cs[2]);
            st_sc1_f2(p + 3, cm[3], cs[3]);
        }
        gbar(cb, b, g, ep);   // batch-local: all partials at coherence point

        // ---- combine + Adam v: block (b,g) handles columns g*32..g*32+31 ----
        {
            const int c32 = tid & 31;
            const int q   = tid >> 5;        // 8 chunks of 4 row-groups
            const float2* pp = part + ((size_t)b * NGRP + q * 4) * MM + (g * 32 + c32);
            float Mc = -3.0e38f, Sc = 0.f;
#pragma unroll
            for (int s5 = 0; s5 < 4; ++s5) {
                const float2 pr = ld_sc1_f2(pp + (size_t)s5 * MM);
                const float mn = fmaxf(Mc, pr.x);
                Sc = Sc * __expf(Mc - mn) + pr.y * __expf(pr.x - mn);
                Mc = mn;
            }
            red2[q][c32] = make_float2(Mc, Sc);
            __syncthreads();
            if (tid < 32) {
                float M = -3.0e38f, S = 0.f;
#pragma unroll
                for (int q2 = 0; q2 < 8; ++q2) {
                    const float2 pr = red2[q2][tid];
                    const float mn = fmaxf(M, pr.x);
                    S = S * __expf(M - mn) + pr.y * __expf(pr.x - mn);
                    M = mn;
                }
                const int i     = b * MM + g * 32 + tid;
                const float lse = M + __logf(S);
                const float vo  = ws[OFF_V + i];
                const float gv  = (log_b[i] - lse) - vo;
                const float m_  = B1f * ws[OFF_MV + i] + (1.f - B1f) * gv;  // private
                const float v_  = B2f * ws[OFF_VV + i] + (1.f - B2f) * gv * gv;
                ws[OFF_MV + i] = m_;
                ws[OFF_VV + i] = v_;
                st_sc1_f(ws + OFF_V + i, vo + LR * (m_ / bc1) / (sqrtf(v_ / bc2) + EPSA));
            }
        }
        gbar(cb, b, g, ep);   // batch-local: fresh v at coherence point
    }

    // ---- finalize: out = exp(K/tau + u + v), arg-clamped ----
    const float4 vf = ld_sc1_f4(ws + OFF_V + b * MM + 4 * tid);
    float* ob = out + ((size_t)b * NN + row0) * MM + 4 * tid;
#pragma unroll
    for (int r = 0; r < RREG; ++r) {
        const float uu = su[r];
        float4 o;
        o.x = __expf(fminf(kr[r][0] + uu + vf.x, EXP_CAP));
        o.y = __expf(fminf(kr[r][1] + uu + vf.y, EXP_CAP));
        o.z = __expf(fminf(kr[r][2] + uu + vf.z, EXP_CAP));
        o.w = __expf(fminf(kr[r][3] + uu + vf.w, EXP_CAP));
        *(float4*)(ob + (size_t)r * MM) = o;
    }
#pragma unroll
    for (int r = 0; r < RLDS; ++r) {
        const float4 k4 = *(const float4*)(&klds[r][4 * tid]);
        const float uu = su[RREG + r];
        float4 o;
        o.x = __expf(fminf(k4.x + uu + vf.x, EXP_CAP));
        o.y = __expf(fminf(k4.y + uu + vf.y, EXP_CAP));
        o.z = __expf(fminf(k4.z + uu + vf.z, EXP_CAP));
        o.w = __expf(fminf(k4.w + uu + vf.w, EXP_CAP));
        *(float4*)(ob + (size_t)(RREG + r) * MM) = o;
    }
}

// ============================================================================
// Legacy fallback path (the verified 339 us kernel) — used only if the
// cooperative launch is rejected.
// ============================================================================
__global__ __launch_bounds__(256, 4) void iter_fused(
    const float* __restrict__ la, const float* __restrict__ log_a,
    float* __restrict__ ws, float2* __restrict__ part,
    float bc1, float bc2)
{
    const int slab = blockIdx.x;
    const int b    = blockIdx.y;
    const int row0 = slab * RPB8;
    const int tid  = threadIdx.x;
    const int wave = tid >> 6;
    const int lane = tid & 63;
    __shared__ float redm[4 * RPB8];
    __shared__ float reds[4 * RPB8];
    __shared__ float fin[RPB8];
    __shared__ float su[RPB8];

    const float* Kb = la + ((size_t)b * NN + row0) * MM + 4 * tid;
    float kr[RPB8][4];
#pragma unroll
    for (int r = 0; r < RPB8; ++r) {
        const float4 k4 = *(const float4*)(Kb + (size_t)r * MM);
        kr[r][0] = k4.x * INV_TAU; kr[r][1] = k4.y * INV_TAU;
        kr[r][2] = k4.z * INV_TAU; kr[r][3] = k4.w * INV_TAU;
    }
    const float4 v4 = *(const float4*)(ws + OFF_V + b * MM + 4 * tid);
    const float vj[4] = {v4.x, v4.y, v4.z, v4.w};

    float pm[RPB8];
#pragma unroll
    for (int r = 0; r < RPB8; ++r)
        pm[r] = fmaxf(fmaxf(kr[r][0] + vj[0], kr[r][1] + vj[1]),
                      fmaxf(kr[r][2] + vj[2], kr[r][3] + vj[3]));
#pragma unroll
    for (int off = 32; off; off >>= 1)
#pragma unroll
        for (int r = 0; r < RPB8; ++r)
            pm[r] = fmaxf(pm[r], __shfl_xor(pm[r], off, 64));
    if (lane == 0)
#pragma unroll
        for (int r = 0; r < RPB8; ++r) redm[wave * RPB8 + r] = pm[r];
    __syncthreads();
    if (tid < RPB8)
        fin[tid] = fmaxf(fmaxf(redm[tid], redm[RPB8 + tid]),
                         fmaxf(redm[2 * RPB8 + tid], redm[3 * RPB8 + tid]));
    __syncthreads();
    float Mr[RPB8];
#pragma unroll
    for (int r = 0; r < RPB8; ++r) Mr[r] = fin[r];

    float ps[RPB8];
#pragma unroll
    for (int r = 0; r < RPB8; ++r)
        ps[r] = __expf(kr[r][0] + vj[0] - Mr[r]) + __expf(kr[r][1] + vj[1] - Mr[r])
              + __expf(kr[r][2] + vj[2] - Mr[r]) + __expf(kr[r][3] + vj[3] - Mr[r]);
#pragma unroll
    for (int off = 32; off; off >>= 1)
#pragma unroll
        for (int r = 0; r < RPB8; ++r)
            ps[r] += __shfl_xor(ps[r], off, 64);
    if (lane == 0)
#pragma unroll
        for (int r = 0; r < RPB8; ++r) reds[wave * RPB8 + r] = ps[r];
    __syncthreads();
    if (tid < RPB8) {
        const int r  = tid;
        const int gi = b * NN + row0 + r;
        const float S   = reds[r] + reds[RPB8 + r] + reds[2 * RPB8 + r] + reds[3 * RPB8 + r];
        const float lse = Mr[r] + __logf(S);
        const float uo  = ws[OFF_U + gi];
        const float gu  = (log_a[gi] - lse) - uo;
        const float m_  = B1f * ws[OFF_MU + gi] + (1.f - B1f) * gu;
        const float v_  = B2f * ws[OFF_VU + gi] + (1.f - B2f) * gu * gu;
        ws[OFF_MU + gi] = m_;
        ws[OFF_VU + gi] = v_;
        const float un  = uo + LR * (m_ / bc1) / (sqrtf(v_ / bc2) + EPSA);
        ws[OFF_U + gi]  = un;
        su[r] = un;
    }
    __syncthreads();
    float uu[RPB8];
#pragma unroll
    for (int r = 0; r < RPB8; ++r) uu[r] = su[r];

    float2 out4[4];
#pragma unroll
    for (int j = 0; j < 4; ++j) {
        float m = kr[0][j] + uu[0];
#pragma unroll
        for (int r = 1; r < RPB8; ++r) m = fmaxf(m, kr[r][j] + uu[r]);
        float s = 0.f;
#pragma unroll
        for (int r = 0; r < RPB8; ++r) s += __expf(kr[r][j] + uu[r] - m);
        out4[j] = make_float2(m, s);
    }
    float2* p = part + ((size_t)b * NSLAB + slab) * MM + 4 * tid;
    p[0] = out4[0]; p[1] = out4[1]; p[2] = out4[2]; p[3] = out4[3];
}

__global__ __launch_bounds__(256, 8) void combine_legacy(
    const float* __restrict__ log_b, float* __restrict__ ws,
    const float2* __restrict__ part, float bc1, float bc2)
{
    const int b   = blockIdx.x >> 4;
    const int mg  = blockIdx.x & 15;
    const int tid = threadIdx.x;
    const int c   = tid & 63;
    const int q   = tid >> 6;
    const int m   = mg * 64 + c;
    __shared__ float2 red[4][64];

    const float2* p = part + ((size_t)b * NSLAB + q * 32) * MM + m;
    float M = -3.0e38f, S = 0.f;
#pragma unroll 8
    for (int s = 0; s < 32; ++s) {
        const float2 pr = p[(size_t)s * MM];
        const float mn = fmaxf(M, pr.x);
        S = S * __expf(M - mn) + pr.y * __expf(pr.x - mn);
        M = mn;
    }
    red[q][c] = make_float2(M, S);
    __syncthreads();
    if (q == 0) {
        const float2 a = red[0][c], bb = red[1][c], cc = red[2][c], d = red[3][c];
        const float Mt = fmaxf(fmaxf(a.x, bb.x), fmaxf(cc.x, d.x));
        const float St = a.y * __expf(a.x - Mt) + bb.y * __expf(bb.x - Mt)
                       + cc.y * __expf(cc.x - Mt) + d.y * __expf(d.x - Mt);
        const int i = b * MM + m;
        const float lse = Mt + __logf(St);
        const float vo  = ws[OFF_V + i];
        const float gv  = (log_b[i] - lse) - vo;
        const float m_  = B1f * ws[OFF_MV + i] + (1.f - B1f) * gv;
        const float v_  = B2f * ws[OFF_VV + i] + (1.f - B2f) * gv * gv;
        ws[OFF_MV + i] = m_;
        ws[OFF_VV + i] = v_;
        ws[OFF_V + i]  = vo + LR * (m_ / bc1) / (sqrtf(v_ / bc2) + EPSA);
    }
}

__global__ void finalize_legacy(const float* __restrict__ la, const float* __restrict__ ws,
                                float* __restrict__ out)
{
    const size_t i4 = (size_t)blockIdx.x * 256 + threadIdx.x;
    const size_t e  = i4 * 4;
    const int row = (int)(e >> 10);
    const int b   = row >> 10;
    const int m   = (int)(e & 1023);
    const float uu = ws[OFF_U + row];
    const float4 k4 = ((const float4*)la)[i4];
    const float4 v4 = *(const float4*)(ws + OFF_V + b * MM + m);
    float4 o;
    o.x = __expf(fminf(k4.x * INV_TAU + uu + v4.x, EXP_CAP));
    o.y = __expf(fminf(k4.y * INV_TAU + uu + v4.y, EXP_CAP));
    o.z = __expf(fminf(k4.z * INV_TAU + uu + v4.z, EXP_CAP));
    o.w = __expf(fminf(k4.w * INV_TAU + uu + v4.w, EXP_CAP));
    ((float4*)out)[i4] = o;
}

extern "C" void kernel_launch(void* const* d_in, const int* in_sizes, int n_in,
                              void* d_out, int out_size, void* d_ws, size_t ws_size,
                              hipStream_t stream) {
    const float* la    = (const float*)d_in[0];
    const float* log_a = (const float*)d_in[1];
    const float* log_b = (const float*)d_in[2];
    float*  out  = (float*)d_out;
    float*  ws   = (float*)d_ws;
    float2* part = (float2*)(ws + OFF_PART);

    // Zero Adam state + barrier region (graph-safe, replay-safe).
    hipMemsetAsync(d_ws, 0, OFF_PART * sizeof(float), stream);

    void* args[] = {(void*)&la, (void*)&log_a, (void*)&log_b,
                    (void*)&ws, (void*)&part, (void*)&out};
    hipError_t err = hipLaunchCooperativeKernel(
        (const void*)sinkhorn_persistent, dim3(NBLK), dim3(256), args, 0, stream);

    if (err != hipSuccess) {
        // Fallback: previous verified multi-kernel path (339 us).
        for (int t = 1; t <= 10; ++t) {
            const float bc1 = 1.0f - powf(B1f, (float)t);
            const float bc2 = 1.0f - powf(B2f, (float)t);
            iter_fused<<<dim3(NSLAB, BB), 256, 0, stream>>>(la, log_a, ws, part, bc1, bc2);
            combine_legacy<<<BB * MM / 256, 256, 0, stream>>>(log_b, ws, part, bc1, bc2);
        }
        finalize_legacy<<<16384, 256, 0, stream>>>(la, ws, out);
    }
}

// Round 10
// 344.471 us; speedup vs baseline: 8.0023x; 1.1209x over previous
//
#include <hip/hip_runtime.h>
#include <cmath>

#define BB 16
#define NN 1024
#define MM 1024

// ---- persistent-kernel geometry (R7/R8-verified spill-free) ----
// 512 blocks x 256 threads. waves_per_eu(2,2) + 67.5KB LDS pin EXACTLY
// 2 blocks/CU -> 256 CU x 2 = 512 co-resident: a regular launch is de-facto
// cooperative (all blocks placed before any can retire; all spin at gbar).
// Empirical allocator law (R2/R3/R6): granted VGPR = 512/(2*waves_min) = 128.
// Demand: kr[16][4]=64 + ~50 working = ~114 <= 128 -> no spill (R5/R7/R8).
#define RPB   32           // rows per block
#define RREG  16           // rows kept in registers
#define RLDS  (RPB - RREG) // 16 rows in LDS
#define NGRP  (NN / RPB)   // 32 row-groups per batch
#define NBLK  (BB * NGRP)  // 512 blocks

// log2-domain: K scaled by (1/tau)*log2(e); u,v,Adam moments all in log2
// units. Adam's update ratio m/(sqrt(v)+eps) is scale-invariant (eps shift
// ~1e-8 relative, negligible), so u2 = log2e * u_ref exactly up to fp.
static constexpr float L2E   = 1.4426950408889634f;
static constexpr float SCALE = 20.0f * 1.4426950408889634f;  // INV_TAU * L2E
static constexpr float LR    = 0.5f;
static constexpr float B1f   = 0.9f;
static constexpr float B2f   = 0.999f;
static constexpr float EPSA  = 1e-8f;
static constexpr float CAP2  = 126.0f;   // exp2 arg clamp (fast-math safe)

// Raw gfx950 transcendentals (avoid glibc __exp2f/__log2f name collision:
// math.h declares host __exp2f via __MATHDECL — the R9 compile failure).
// v_exp_f32 computes 2^x, v_log_f32 computes log2(x) (ISA §3).
__device__ __forceinline__ float ex2(float x) { return __builtin_amdgcn_exp2f(x); }
__device__ __forceinline__ float lg2(float x) { return __builtin_amdgcn_logf(x); }

// d_ws layout (floats): u v mu vu mv vv | barrier region | part region.
#define OFF_U    0
#define OFF_V    16384
#define OFF_MU   32768
#define OFF_VU   49152
#define OFF_MV   65536
#define OFF_VV   81920
#define OFF_CNT  98304     // int region: slots[16][64] then flags[16*32]
#define OFF_PART 102400    // float2 region: [BB][NGRP][MM] = 4 MB

#define FLAG_BASE 1024     // int offset of flags within barrier region

// ---- sc1 (device-coherent) accessors for SHARED data only ----
__device__ __forceinline__ void st_sc1_f2(float2* p, float mx, float sy) {
    union { float2 f; unsigned long long u; } cv; cv.f = make_float2(mx, sy);
    __hip_atomic_store((unsigned long long*)p, cv.u, __ATOMIC_RELAXED, __HIP_MEMORY_SCOPE_AGENT);
}
__device__ __forceinline__ float2 ld_sc1_f2(const float2* p) {
    union { float2 f; unsigned long long u; } cv;
    cv.u = __hip_atomic_load((unsigned long long*)p, __ATOMIC_RELAXED, __HIP_MEMORY_SCOPE_AGENT);
    return cv.f;
}
__device__ __forceinline__ void st_sc1_f(float* p, float v) {
    union { float f; unsigned u; } cv; cv.f = v;
    __hip_atomic_store((unsigned*)p, cv.u, __ATOMIC_RELAXED, __HIP_MEMORY_SCOPE_AGENT);
}
__device__ __forceinline__ float4 ld_sc1_f4(const float* p) {
    const float2 a = ld_sc1_f2((const float2*)p);
    const float2 b = ld_sc1_f2((const float2*)(p + 2));
    return make_float4(a.x, a.y, b.x, b.y);
}

// ---- per-batch barrier: store-slot + lane-parallel poll, zero RMWs ----
// (R8-verified passing.) Arrival: thread 0 stores slot[b][g]=ep. Leader block
// (g==0): wave 0 polls slots, __all(slot>=ep) -> flag[b]=ep. Followers spin
// on the flag. Entry __syncthreads drains each wave's vmcnt before s_barrier,
// so slot/flag stores issue only after the block's data stores.
__device__ __forceinline__ void gbar(int* cb, int b, int g, int& ep) {
    __syncthreads();
    ++ep;
    const int tid = threadIdx.x;
    if (tid == 0)
        __hip_atomic_store(cb + b * 64 + g, ep,
                           __ATOMIC_RELAXED, __HIP_MEMORY_SCOPE_AGENT);
    if (g == 0) {
        if (tid < 64) {
            for (;;) {
                const int v = __hip_atomic_load(cb + b * 64 + (tid & 31),
                                __ATOMIC_RELAXED, __HIP_MEMORY_SCOPE_AGENT);
                if (__all(v >= ep)) break;
                __builtin_amdgcn_s_sleep(1);
            }
            if (tid == 0)
                __hip_atomic_store(cb + FLAG_BASE + b * 32, ep,
                                   __ATOMIC_RELAXED, __HIP_MEMORY_SCOPE_AGENT);
        }
    } else if (tid == 0) {
        while (__hip_atomic_load(cb + FLAG_BASE + b * 32,
                 __ATOMIC_RELAXED, __HIP_MEMORY_SCOPE_AGENT) < ep)
            __builtin_amdgcn_s_sleep(1);
    }
    __syncthreads();
}

// ============================================================================
// Persistent kernel, log2 domain. Block (b,g) owns rows g*32..g*32+31 of
// batch b; thread tid owns columns 4*tid..4*tid+3. Rows 0-15 in VGPRs,
// 16-31 in LDS. Fused row pass: t=k2+v2 once, wave max butterfly, exp2-sum
// butterfly, single LDS cross-wave (m,s) rescale-combine.
// ============================================================================
__global__ __launch_bounds__(256)
__attribute__((amdgpu_waves_per_eu(2, 2)))
void sinkhorn_persistent(
    const float* __restrict__ la, const float* __restrict__ log_a,
    const float* __restrict__ log_b, float* __restrict__ ws,
    float2* __restrict__ part, float* __restrict__ out)
{
    const int bid  = blockIdx.x;
    const int b    = bid >> 5;          // batch
    const int g    = bid & 31;          // row-group AND column-group
    const int row0 = g * RPB;
    const int tid  = threadIdx.x;
    const int wave = tid >> 6;
    const int lane = tid & 63;

    __shared__ float  klds[RLDS][MM];   // rows 16-31, pre-scaled (64 KB)
    __shared__ float  redm[4 * RPB];    // [wave][row] wave-local max
    __shared__ float  reds[4 * RPB];    // [wave][row] wave-local exp2-sum
    __shared__ float  su[RPB];          // fresh u2 for this block's rows
    __shared__ float2 red2[8][32];      // combine: [chunk][col32]

    int* cb = (int*)ws + OFF_CNT;
    int ep = 0;

    // ---- load K slab, pre-scaled to log2 domain ----
    const float* Kb = la + ((size_t)b * NN + row0) * MM + 4 * tid;
    float kr[RREG][4];
#pragma unroll
    for (int r = 0; r < RREG; ++r) {
        const float4 k4 = *(const float4*)(Kb + (size_t)r * MM);
        kr[r][0] = k4.x * SCALE; kr[r][1] = k4.y * SCALE;
        kr[r][2] = k4.z * SCALE; kr[r][3] = k4.w * SCALE;
    }
#pragma unroll
    for (int r = 0; r < RLDS; ++r) {
        float4 k4 = *(const float4*)(Kb + (size_t)(RREG + r) * MM);
        k4.x *= SCALE; k4.y *= SCALE; k4.z *= SCALE; k4.w *= SCALE;
        *(float4*)(&klds[r][4 * tid]) = k4;
    }
    __syncthreads();

    float pb1 = 1.0f, pb2 = 1.0f;
    for (int t = 0; t < 10; ++t) {
        pb1 *= B1f; pb2 *= B2f;
        const float bc1 = 1.0f - pb1, bc2 = 1.0f - pb2;

        // ---- fused row pass: wave-local (max, exp2-sum) per row ----
        const float4 v4 = ld_sc1_f4(ws + OFF_V + b * MM + 4 * tid);
#pragma unroll
        for (int r = 0; r < RREG; ++r) {
            const float t0 = kr[r][0] + v4.x, t1 = kr[r][1] + v4.y;
            const float t2 = kr[r][2] + v4.z, t3 = kr[r][3] + v4.w;
            float m = fmaxf(fmaxf(t0, t1), fmaxf(t2, t3));
#pragma unroll
            for (int off = 32; off; off >>= 1) m = fmaxf(m, __shfl_xor(m, off, 64));
            float s = ex2(t0 - m) + ex2(t1 - m) + ex2(t2 - m) + ex2(t3 - m);
#pragma unroll
            for (int off = 32; off; off >>= 1) s += __shfl_xor(s, off, 64);
            if (lane == 0) { redm[wave * RPB + r] = m; reds[wave * RPB + r] = s; }
        }
#pragma unroll
        for (int r = 0; r < RLDS; ++r) {
            const float4 k4 = *(const float4*)(&klds[r][4 * tid]);
            const float t0 = k4.x + v4.x, t1 = k4.y + v4.y;
            const float t2 = k4.z + v4.z, t3 = k4.w + v4.w;
            float m = fmaxf(fmaxf(t0, t1), fmaxf(t2, t3));
#pragma unroll
            for (int off = 32; off; off >>= 1) m = fmaxf(m, __shfl_xor(m, off, 64));
            float s = ex2(t0 - m) + ex2(t1 - m) + ex2(t2 - m) + ex2(t3 - m);
#pragma unroll
            for (int off = 32; off; off >>= 1) s += __shfl_xor(s, off, 64);
            if (lane == 0) { redm[wave * RPB + RREG + r] = m; reds[wave * RPB + RREG + r] = s; }
        }
        __syncthreads();
        if (tid < RPB) {
            const int r  = tid;
            const int gi = b * NN + row0 + r;
            const float m0 = redm[r],           s0 = reds[r];
            const float m1 = redm[RPB + r],     s1 = reds[RPB + r];
            const float m2 = redm[2 * RPB + r], s2 = reds[2 * RPB + r];
            const float m3 = redm[3 * RPB + r], s3 = reds[3 * RPB + r];
            const float M  = fmaxf(fmaxf(m0, m1), fmaxf(m2, m3));
            const float S  = s0 * ex2(m0 - M) + s1 * ex2(m1 - M)
                           + s2 * ex2(m2 - M) + s3 * ex2(m3 - M);
            const float lse2 = M + lg2(S);
            const float uo  = ws[OFF_U + gi];                      // private
            const float gu  = (log_a[gi] * L2E - lse2) - uo;
            const float m_  = B1f * ws[OFF_MU + gi] + (1.f - B1f) * gu;
            const float v_  = B2f * ws[OFF_VU + gi] + (1.f - B2f) * gu * gu;
            ws[OFF_MU + gi] = m_;
            ws[OFF_VU + gi] = v_;
            const float un  = uo + LR * (m_ / bc1) / (sqrtf(v_ / bc2) + EPSA);
            ws[OFF_U + gi]  = un;
            su[r] = un;
        }
        __syncthreads();

        // ---- col partials: exact two-pass over regs + LDS rows ----
        {
            float cm[4];
#pragma unroll
            for (int j = 0; j < 4; ++j) cm[j] = kr[0][j] + su[0];
#pragma unroll
            for (int r = 1; r < RREG; ++r) {
                const float sr = su[r];
                cm[0] = fmaxf(cm[0], kr[r][0] + sr);
                cm[1] = fmaxf(cm[1], kr[r][1] + sr);
                cm[2] = fmaxf(cm[2], kr[r][2] + sr);
                cm[3] = fmaxf(cm[3], kr[r][3] + sr);
            }
#pragma unroll
            for (int r = 0; r < RLDS; ++r) {
                const float4 k4 = *(const float4*)(&klds[r][4 * tid]);
                const float sr = su[RREG + r];
                cm[0] = fmaxf(cm[0], k4.x + sr);
                cm[1] = fmaxf(cm[1], k4.y + sr);
                cm[2] = fmaxf(cm[2], k4.z + sr);
                cm[3] = fmaxf(cm[3], k4.w + sr);
            }
            float cs[4] = {0.f, 0.f, 0.f, 0.f};
#pragma unroll
            for (int r = 0; r < RREG; ++r) {
                const float sr = su[r];
                cs[0] += ex2(kr[r][0] + sr - cm[0]);
                cs[1] += ex2(kr[r][1] + sr - cm[1]);
                cs[2] += ex2(kr[r][2] + sr - cm[2]);
                cs[3] += ex2(kr[r][3] + sr - cm[3]);
            }
#pragma unroll
            for (int r = 0; r < RLDS; ++r) {
                const float4 k4 = *(const float4*)(&klds[r][4 * tid]);
                const float sr = su[RREG + r];
                cs[0] += ex2(k4.x + sr - cm[0]);
                cs[1] += ex2(k4.y + sr - cm[1]);
                cs[2] += ex2(k4.z + sr - cm[2]);
                cs[3] += ex2(k4.w + sr - cm[3]);
            }
            float2* p = part + ((size_t)b * NGRP + g) * MM + 4 * tid;
            st_sc1_f2(p + 0, cm[0], cs[0]);
            st_sc1_f2(p + 1, cm[1], cs[1]);
            st_sc1_f2(p + 2, cm[2], cs[2]);
            st_sc1_f2(p + 3, cm[3], cs[3]);
        }
        gbar(cb, b, g, ep);   // batch-local: all partials at coherence point

        // ---- combine + Adam v: block (b,g) handles columns g*32..g*32+31 ----
        {
            const int c32 = tid & 31;
            const int q   = tid >> 5;        // 8 chunks of 4 row-groups
            const float2* pp = part + ((size_t)b * NGRP + q * 4) * MM + (g * 32 + c32);
            float Mc = -3.0e38f, Sc = 0.f;
#pragma unroll
            for (int s5 = 0; s5 < 4; ++s5) {
                const float2 pr = ld_sc1_f2(pp + (size_t)s5 * MM);
                const float mn = fmaxf(Mc, pr.x);
                Sc = Sc * ex2(Mc - mn) + pr.y * ex2(pr.x - mn);
                Mc = mn;
            }
            red2[q][c32] = make_float2(Mc, Sc);
            __syncthreads();
            if (tid < 32) {
                float M = -3.0e38f, S = 0.f;
#pragma unroll
                for (int q2 = 0; q2 < 8; ++q2) {
                    const float2 pr = red2[q2][tid];
                    const float mn = fmaxf(M, pr.x);
                    S = S * ex2(M - mn) + pr.y * ex2(pr.x - mn);
                    M = mn;
                }
                const int i     = b * MM + g * 32 + tid;
                const float lse2 = M + lg2(S);
                const float vo  = ws[OFF_V + i];
                const float gv  = (log_b[i] * L2E - lse2) - vo;
                const float m_  = B1f * ws[OFF_MV + i] + (1.f - B1f) * gv;  // private
                const float v_  = B2f * ws[OFF_VV + i] + (1.f - B2f) * gv * gv;
                ws[OFF_MV + i] = m_;
                ws[OFF_VV + i] = v_;
                st_sc1_f(ws + OFF_V + i, vo + LR * (m_ / bc1) / (sqrtf(v_ / bc2) + EPSA));
            }
        }
        gbar(cb, b, g, ep);   // batch-local: fresh v at coherence point
    }

    // ---- finalize: out = exp2(k2 + u2 + v2), arg-clamped ----
    const float4 vf = ld_sc1_f4(ws + OFF_V + b * MM + 4 * tid);
    float* ob = out + ((size_t)b * NN + row0) * MM + 4 * tid;
#pragma unroll
    for (int r = 0; r < RREG; ++r) {
        const float uu = su[r];
        float4 o;
        o.x = ex2(fminf(kr[r][0] + uu + vf.x, CAP2));
        o.y = ex2(fminf(kr[r][1] + uu + vf.y, CAP2));
        o.z = ex2(fminf(kr[r][2] + uu + vf.z, CAP2));
        o.w = ex2(fminf(kr[r][3] + uu + vf.w, CAP2));
        *(float4*)(ob + (size_t)r * MM) = o;
    }
#pragma unroll
    for (int r = 0; r < RLDS; ++r) {
        const float4 k4 = *(const float4*)(&klds[r][4 * tid]);
        const float uu = su[RREG + r];
        float4 o;
        o.x = ex2(fminf(k4.x + uu + vf.x, CAP2));
        o.y = ex2(fminf(k4.y + uu + vf.y, CAP2));
        o.z = ex2(fminf(k4.z + uu + vf.z, CAP2));
        o.w = ex2(fminf(k4.w + uu + vf.w, CAP2));
        *(float4*)(ob + (size_t)(RREG + r) * MM) = o;
    }
}

extern "C" void kernel_launch(void* const* d_in, const int* in_sizes, int n_in,
                              void* d_out, int out_size, void* d_ws, size_t ws_size,
                              hipStream_t stream) {
    const float* la    = (const float*)d_in[0];
    const float* log_a = (const float*)d_in[1];
    const float* log_b = (const float*)d_in[2];
    float*  out  = (float*)d_out;
    float*  ws   = (float*)d_ws;
    float2* part = (float2*)(ws + OFF_PART);

    // Zero Adam state + barrier region (graph-safe, replay-safe).
    hipMemsetAsync(d_ws, 0, OFF_PART * sizeof(float), stream);

    // Regular launch: grid 512 == exact co-residency capacity (2 blocks/CU
    // pinned by waves_per_eu(2,2) + 67.5KB LDS), so all blocks are placed
    // before any can retire (all spin at gbar) — de-facto cooperative,
    // without hipLaunchCooperativeKernel's per-replay overhead.
    sinkhorn_persistent<<<dim3(NBLK), dim3(256), 0, stream>>>(
        la, log_a, log_b, ws, part, out);
}